// Round 1
// baseline (1770.272 us; speedup 1.0000x reference)
//
#include <hip/hip_runtime.h>
#include <stdint.h>
#include <stddef.h>

#define BB 8
#define NN 4096
#define MTOK 1024
#define DD 1024
#define HH 16
#define EPSF 1e-6f
static const float SCALE_F = 0.125f; // HD^-0.5, HD=64

typedef __attribute__((ext_vector_type(4))) float f32x4;
typedef __attribute__((ext_vector_type(8))) short bf16x8;

__device__ __forceinline__ short f2bf(float f) {
  union { float f; uint32_t u; } x; x.f = f;
  uint32_t r = (x.u + 0x7fffu + ((x.u >> 16) & 1u)) >> 16;
  return (short)(uint16_t)r;
}
__device__ __forceinline__ float bf2f(short s) {
  union { uint32_t u; float f; } x; x.u = ((uint32_t)(uint16_t)s) << 16;
  return x.f;
}

#if defined(__HIP_DEVICE_COMPILE__) && __has_builtin(__builtin_amdgcn_global_load_lds)
#define USE_GLOAD_LDS 1
#else
#define USE_GLOAD_LDS 0
#endif

// ---------------------------------------------------------------------------
// bf16 GEMM, C = A[M,K] @ B^T[N,K]^T + bias, m97-style 128x128 tile, BK=32.
// EPI: 0 = f32 out (acc+bias); 1 = f32 out (acc+bias+resid);
//      2 = bf16 out (acc+bias); 3 = bf16 out silu(acc+bias)
// ---------------------------------------------------------------------------
template <int EPI>
__global__ __launch_bounds__(256) void gemm_bf16(
    const short* __restrict__ A, const short* __restrict__ BT,
    const float* __restrict__ bias, const float* __restrict__ resid,
    void* __restrict__ outp, int N, int K, int lda, int ldb) {
  const int t = threadIdx.x;
  const int w = t >> 6;
  const int lane = t & 63;
  const int bm = blockIdx.x, bn = blockIdx.y;
  const int wr = w >> 1, wc = w & 1;

  __shared__ short As[4096];
  __shared__ short Bs[4096];

  f32x4 acc[4][4];
#pragma unroll
  for (int i = 0; i < 4; ++i)
#pragma unroll
    for (int j = 0; j < 4; ++j) acc[i][j] = (f32x4){0.f, 0.f, 0.f, 0.f};

  const short* ag = A + (long)(bm * 128 + (t >> 2)) * lda + (t & 3) * 8;
  const short* bg = BT + (long)(bn * 128 + (t >> 2)) * ldb + (t & 3) * 8;

  for (int k0 = 0; k0 < K; k0 += 32) {
    __syncthreads();
#if USE_GLOAD_LDS
#pragma unroll
    for (int j = 0; j < 2; ++j) {
      __builtin_amdgcn_global_load_lds(
          (__attribute__((address_space(1))) void*)(void*)(ag + (long)j * 64 * lda + k0),
          (__attribute__((address_space(3))) void*)(&As[j * 2048 + w * 512]), 16, 0, 0);
      __builtin_amdgcn_global_load_lds(
          (__attribute__((address_space(1))) void*)(void*)(bg + (long)j * 64 * ldb + k0),
          (__attribute__((address_space(3))) void*)(&Bs[j * 2048 + w * 512]), 16, 0, 0);
    }
#else
#pragma unroll
    for (int j = 0; j < 2; ++j) {
      *(bf16x8*)&As[j * 2048 + t * 8] = *(const bf16x8*)(ag + (long)j * 64 * lda + k0);
      *(bf16x8*)&Bs[j * 2048 + t * 8] = *(const bf16x8*)(bg + (long)j * 64 * ldb + k0);
    }
#endif
    __syncthreads();
    bf16x8 af[4], bfr[4];
#pragma unroll
    for (int mi = 0; mi < 4; ++mi)
      af[mi] = *(const bf16x8*)&As[(wr * 64 + mi * 16 + (lane & 15)) * 32 + (lane >> 4) * 8];
#pragma unroll
    for (int ni = 0; ni < 4; ++ni)
      bfr[ni] = *(const bf16x8*)&Bs[(wc * 64 + ni * 16 + (lane & 15)) * 32 + (lane >> 4) * 8];
#pragma unroll
    for (int mi = 0; mi < 4; ++mi)
#pragma unroll
      for (int ni = 0; ni < 4; ++ni)
        acc[mi][ni] = __builtin_amdgcn_mfma_f32_16x16x32_bf16(af[mi], bfr[ni], acc[mi][ni], 0, 0, 0);
  }

  const int r0 = bm * 128 + wr * 64 + ((lane >> 4) << 2);
  const int c0 = bn * 128 + wc * 64 + (lane & 15);
#pragma unroll
  for (int mi = 0; mi < 4; ++mi) {
#pragma unroll
    for (int ni = 0; ni < 4; ++ni) {
      const int col = c0 + ni * 16;
      const float bv = bias ? bias[col] : 0.f;
#pragma unroll
      for (int rr = 0; rr < 4; ++rr) {
        const int row = r0 + mi * 16 + rr;
        const long idx = (long)row * N + col;
        float v = acc[mi][ni][rr] + bv;
        if (EPI == 0) {
          ((float*)outp)[idx] = v;
        } else if (EPI == 1) {
          ((float*)outp)[idx] = v + resid[idx];
        } else if (EPI == 2) {
          ((short*)outp)[idx] = f2bf(v);
        } else {
          v = v / (1.f + __expf(-v));
          ((short*)outp)[idx] = f2bf(v);
        }
      }
    }
  }
}

// ---------------------------------------------------------------------------
// Row LayerNorm over D=1024, fp32 in -> bf16 out. One block (256 thr) per row.
// ---------------------------------------------------------------------------
__global__ __launch_bounds__(256) void ln_rows(const float* __restrict__ in,
                                               const float* __restrict__ g,
                                               const float* __restrict__ bta,
                                               short* __restrict__ outp) {
  const int row = blockIdx.x;
  const int t = threadIdx.x;
  const float4 v = ((const float4*)(in + (long)row * DD))[t];
  float s = v.x + v.y + v.z + v.w;
  float ss = v.x * v.x + v.y * v.y + v.z * v.z + v.w * v.w;
#pragma unroll
  for (int off = 1; off < 64; off <<= 1) {
    s += __shfl_xor(s, off);
    ss += __shfl_xor(ss, off);
  }
  __shared__ float red[8];
  const int w = t >> 6, lane = t & 63;
  if (lane == 0) { red[w] = s; red[4 + w] = ss; }
  __syncthreads();
  s = red[0] + red[1] + red[2] + red[3];
  ss = red[4] + red[5] + red[6] + red[7];
  const float mu = s * (1.f / DD);
  const float var = ss * (1.f / DD) - mu * mu;
  const float rs = rsqrtf(var + EPSF);
  const float4 gv = ((const float4*)g)[t];
  const float4 bv = ((const float4*)bta)[t];
  short4 o;
  o.x = f2bf((v.x - mu) * rs * gv.x + bv.x);
  o.y = f2bf((v.y - mu) * rs * gv.y + bv.y);
  o.z = f2bf((v.z - mu) * rs * gv.z + bv.z);
  o.w = f2bf((v.w - mu) * rs * gv.w + bv.w);
  ((short4*)(outp + (long)row * DD))[t] = o;
}

// ---------------------------------------------------------------------------
// Transpose + fp32->bf16 convert: W[K][N] -> WT[N][K]. 64x64 tiles.
// ---------------------------------------------------------------------------
__global__ __launch_bounds__(256) void tconv(const float* __restrict__ W,
                                             short* __restrict__ WT, int K, int N) {
  __shared__ float tile[64][65];
  const int k0 = blockIdx.x * 64, n0 = blockIdx.y * 64;
  const int t = threadIdx.x;
  const int tr = t >> 6, tc = t & 63;
#pragma unroll
  for (int i = 0; i < 64; i += 4)
    tile[i + tr][tc] = W[(long)(k0 + i + tr) * N + n0 + tc];
  __syncthreads();
#pragma unroll
  for (int i = 0; i < 64; i += 4)
    WT[(long)(n0 + i + tr) * K + k0 + tc] = f2bf(tile[tc][i + tr]);
}

// ---------------------------------------------------------------------------
// ctx[b,h,d,e] = sum_m softmax_d(k[b,m,h,:])[d] * v[b,m,h,e].
// kv is bf16 [B*M][2048], k = cols [h*64,h*64+64), v = cols [1024+h*64, ...).
// One block per (b,h); 4 m-rows per iteration (one per wave).
// ---------------------------------------------------------------------------
__global__ __launch_bounds__(256) void ctx_kernel(const short* __restrict__ kv,
                                                  float* __restrict__ ctx) {
  const int bh = blockIdx.x;
  const int b = bh >> 4, h = bh & 15;
  const int t = threadIdx.x, g = t >> 6, lane = t & 63;
  __shared__ float ksm[4][64];
  __shared__ float vsm[4][64];
  float acc[16];
#pragma unroll
  for (int j = 0; j < 16; ++j) acc[j] = 0.f;
  const int d = t & 63;
  const int e0 = (t >> 6) * 16;
  const short* base = kv + (long)b * MTOK * 2048 + h * 64;
  for (int m0 = 0; m0 < MTOK; m0 += 4) {
    const long moff = (long)(m0 + g) * 2048;
    float kval = bf2f(base[moff + lane]);
    float vval = bf2f(base[moff + 1024 + lane]);
    float mx = kval;
#pragma unroll
    for (int off = 1; off < 64; off <<= 1) mx = fmaxf(mx, __shfl_xor(mx, off));
    float e = __expf(kval - mx);
    float sm = e;
#pragma unroll
    for (int off = 1; off < 64; off <<= 1) sm += __shfl_xor(sm, off);
    ksm[g][lane] = e / sm;
    vsm[g][lane] = vval;
    __syncthreads();
#pragma unroll
    for (int mm = 0; mm < 4; ++mm) {
      const float kd = ksm[mm][d];
#pragma unroll
      for (int j = 0; j < 16; ++j) acc[j] = fmaf(kd, vsm[mm][e0 + j], acc[j]);
    }
    __syncthreads();
  }
  float* cp = ctx + ((long)bh * 64 + d) * 64 + e0;
#pragma unroll
  for (int j = 0; j < 16; ++j) cp[j] = acc[j];
}

// ---------------------------------------------------------------------------
// Column softmax stats for q (softmax over the N axis per (b, column)).
// Stage 1: per 128-row chunk online (max,sum). Stage 2: combine 32 chunks.
// ---------------------------------------------------------------------------
__global__ __launch_bounds__(256) void qstat_part(const float* __restrict__ q,
                                                  float* __restrict__ pmax,
                                                  float* __restrict__ psum) {
  const int c = blockIdx.x * 256 + threadIdx.x;
  const int b = blockIdx.z, ch = blockIdx.y;
  const float* qp = q + ((long)b * NN + ch * 128) * DD + c;
  float mx = -1e30f, sm = 0.f;
  for (int r = 0; r < 128; ++r) {
    const float xv = qp[(long)r * DD];
    const float nm = fmaxf(mx, xv);
    sm = sm * __expf(mx - nm) + __expf(xv - nm);
    mx = nm;
  }
  const long idx = ((long)b * DD + c) * 32 + ch;
  pmax[idx] = mx;
  psum[idx] = sm;
}

__global__ __launch_bounds__(256) void qstat_comb(const float* __restrict__ pmax,
                                                  const float* __restrict__ psum,
                                                  float* __restrict__ cmax,
                                                  float* __restrict__ crs) {
  const int i = blockIdx.x * 256 + threadIdx.x;  // b*1024 + c
  const float* pm = pmax + (long)i * 32;
  const float* ps = psum + (long)i * 32;
  float mx = -1e30f;
#pragma unroll
  for (int ch = 0; ch < 32; ++ch) mx = fmaxf(mx, pm[ch]);
  float sm = 0.f;
#pragma unroll
  for (int ch = 0; ch < 32; ++ch) sm += ps[ch] * __expf(pm[ch] - mx);
  cmax[i] = mx;
  crs[i] = SCALE_F / sm;
}

// ---------------------------------------------------------------------------
// Fused: q_soft = exp(q-cmax)*crs (includes SCALE), out = q_soft @ ctx[b,h].
// One block per (b, h, 128 rows). Wave-local LDS row buffer (no barriers in loop).
// ---------------------------------------------------------------------------
__global__ __launch_bounds__(256) void attn_apply(const float* __restrict__ q,
                                                  const float* __restrict__ ctx,
                                                  const float* __restrict__ cmax,
                                                  const float* __restrict__ crs,
                                                  short* __restrict__ outa) {
  const int b = blockIdx.z, h = blockIdx.y, n0 = blockIdx.x * 128;
  const int t = threadIdx.x, g = t >> 6, lane = t & 63;
  __shared__ float ctx_l[4096];
  __shared__ float cm[64], cs[64];
  __shared__ float qsm[4][64];
  const float* cp = ctx + (long)(b * HH + h) * 4096;
  for (int i = t; i < 4096; i += 256) ctx_l[i] = cp[i];
  if (t < 64) {
    cm[t] = cmax[(long)b * DD + h * 64 + t];
    cs[t] = crs[(long)b * DD + h * 64 + t];
  }
  __syncthreads();
  for (int i = 0; i < 32; ++i) {
    const int n = n0 + i * 4 + g;
    const long off = ((long)b * NN + n) * DD + h * 64;
    const float qv = q[off + lane];
    const float qs = __expf(qv - cm[lane]) * cs[lane];
    qsm[g][lane] = qs;  // same-wave LDS, no barrier needed
    float o = 0.f;
#pragma unroll
    for (int dd = 0; dd < 64; ++dd) o = fmaf(qsm[g][dd], ctx_l[dd * 64 + lane], o);
    outa[off + lane] = f2bf(o);
  }
}

// ---------------------------------------------------------------------------
extern "C" void kernel_launch(void* const* d_in, const int* in_sizes, int n_in,
                              void* d_out, int out_size, void* d_ws, size_t ws_size,
                              hipStream_t stream) {
  (void)in_sizes; (void)n_in; (void)out_size;
  const float* x      = (const float*)d_in[0];
  const float* wav    = (const float*)d_in[1];
  const float* ln_q_g = (const float*)d_in[2];
  const float* ln_q_b = (const float*)d_in[3];
  const float* Wq     = (const float*)d_in[4];
  const float* bq     = (const float*)d_in[5];
  const float* ln_kv_g= (const float*)d_in[6];
  const float* ln_kv_b= (const float*)d_in[7];
  const float* Wkv    = (const float*)d_in[8];
  const float* bkv    = (const float*)d_in[9];
  const float* Wo     = (const float*)d_in[10];
  const float* bo     = (const float*)d_in[11];
  const float* ln_f_g = (const float*)d_in[12];
  const float* ln_f_b = (const float*)d_in[13];
  const float* W1     = (const float*)d_in[14];
  const float* b1     = (const float*)d_in[15];
  const float* W2     = (const float*)d_in[16];
  const float* b2     = (const float*)d_in[17];
  float* outp = (float*)d_out;
  char* ws = (char*)d_ws;

  const long MR = (long)BB * NN;   // 32768 rows
  const long MKV = (long)BB * MTOK; // 8192 rows

  size_t off = 0;
  auto bump = [&](size_t bytes) {
    size_t o = off;
    off += (bytes + 255) & ~(size_t)255;
    return o;
  };
  short* WqT  = (short*)(ws + bump((size_t)DD * DD * 2));
  short* WkvT = (short*)(ws + bump((size_t)2048 * DD * 2));
  short* WoT  = (short*)(ws + bump((size_t)DD * DD * 2));
  short* W1T  = (short*)(ws + bump((size_t)4096 * DD * 2));
  short* W2T  = (short*)(ws + bump((size_t)DD * 4096 * 2));
  float* qbuf = (float*)(ws + bump((size_t)MR * DD * 4));   // later: x2 (fp32)
  short* lnbuf= (short*)(ws + bump((size_t)MR * DD * 2));   // xq_ln, later x2_ln
  float* ctx  = (float*)(ws + bump((size_t)BB * HH * 64 * 64 * 4));
  float* pmax = (float*)(ws + bump((size_t)BB * DD * 32 * 4));
  float* psum = (float*)(ws + bump((size_t)BB * DD * 32 * 4));
  float* cmax = (float*)(ws + bump((size_t)BB * DD * 4));
  float* crs  = (float*)(ws + bump((size_t)BB * DD * 4));
  const size_t dyn0 = off;
  short* wvln  = (short*)(ws + dyn0);                         // 16.8 MB
  short* kvbuf = (short*)(ws + dyn0 + (size_t)MKV * DD * 2);  // 33.5 MB (bf16)
  short* oattn = (short*)(ws + dyn0);  // reuses wvln+kv region (dead by then)
  short* hbuf  = (short*)(ws + dyn0);  // MLP phase (oattn dead by then)

  // MLP column-chunk size, shrink if workspace is small
  size_t avail = ws_size > dyn0 ? ws_size - dyn0 : 0;
  int CS = 4096;
  while (CS > 128 && (size_t)MR * CS * 2 > avail) CS >>= 1;

  // 1) weight convert+transpose to bf16 [N][K]
  tconv<<<dim3(DD / 64, DD / 64), 256, 0, stream>>>(Wq, WqT, DD, DD);
  tconv<<<dim3(DD / 64, 2048 / 64), 256, 0, stream>>>(Wkv, WkvT, DD, 2048);
  tconv<<<dim3(DD / 64, DD / 64), 256, 0, stream>>>(Wo, WoT, DD, DD);
  tconv<<<dim3(DD / 64, 4096 / 64), 256, 0, stream>>>(W1, W1T, DD, 4096);
  tconv<<<dim3(4096 / 64, DD / 64), 256, 0, stream>>>(W2, W2T, 4096, DD);

  // 2) LayerNorms -> bf16
  ln_rows<<<dim3((unsigned)MR), 256, 0, stream>>>(x, ln_q_g, ln_q_b, lnbuf);
  ln_rows<<<dim3((unsigned)MKV), 256, 0, stream>>>(wav, ln_kv_g, ln_kv_b, wvln);

  // 3) q = LN(x) @ Wq + bq   (fp32 out, needed for column softmax)
  gemm_bf16<0><<<dim3((unsigned)(MR / 128), DD / 128), 256, 0, stream>>>(
      lnbuf, WqT, bq, nullptr, qbuf, DD, DD, DD, DD);
  // 4) kv = LN(wav) @ Wkv + bkv  (bf16 out)
  gemm_bf16<2><<<dim3((unsigned)(MKV / 128), 2048 / 128), 256, 0, stream>>>(
      wvln, WkvT, bkv, nullptr, kvbuf, 2048, DD, DD, DD);
  // 5) context per (b,h)
  ctx_kernel<<<dim3(BB * HH), 256, 0, stream>>>(kvbuf, ctx);
  // 6) q column-softmax stats
  qstat_part<<<dim3(DD / 256, 32, BB), 256, 0, stream>>>(qbuf, pmax, psum);
  qstat_comb<<<dim3(BB * DD / 256), 256, 0, stream>>>(pmax, psum, cmax, crs);
  // 7) softmax-apply + per-head 64x64 matmul -> out_attn (bf16, overwrites kv)
  attn_apply<<<dim3(NN / 128, HH, BB), 256, 0, stream>>>(qbuf, ctx, cmax, crs, oattn);
  // 8) x2 = out_attn @ Wo + bo + x   (fp32, overwrites q)
  gemm_bf16<1><<<dim3((unsigned)(MR / 128), DD / 128), 256, 0, stream>>>(
      oattn, WoT, bo, x, qbuf, DD, DD, DD, DD);
  float* x2 = qbuf;
  // 9) LN_f(x2) -> bf16
  ln_rows<<<dim3((unsigned)MR), 256, 0, stream>>>(x2, ln_f_g, ln_f_b, lnbuf);
  // 10) MLP: h = silu(x2ln @ W1 + b1); out = x2 + h @ W2 + b2  (chunked over 4096)
  for (int c0 = 0; c0 < 4096; c0 += CS) {
    gemm_bf16<3><<<dim3((unsigned)(MR / 128), CS / 128), 256, 0, stream>>>(
        lnbuf, W1T + (long)c0 * DD, b1 + c0, nullptr, hbuf, CS, DD, DD, DD);
    gemm_bf16<1><<<dim3((unsigned)(MR / 128), DD / 128), 256, 0, stream>>>(
        hbuf, W2T + c0, (c0 == 0) ? b2 : nullptr,
        (c0 == 0) ? (const float*)x2 : (const float*)outp, outp, DD, CS, CS, 4096);
  }
}

// Round 2
// 1401.217 us; speedup vs baseline: 1.2634x; 1.2634x over previous
//
#include <hip/hip_runtime.h>
#include <stdint.h>
#include <stddef.h>

#define BB 8
#define NN 4096
#define MTOK 1024
#define DD 1024
#define HH 16
#define EPSF 1e-6f
static const float SCALE_F = 0.125f; // HD^-0.5, HD=64

typedef __attribute__((ext_vector_type(4))) float f32x4;
typedef __attribute__((ext_vector_type(8))) short bf16x8;

__device__ __forceinline__ short f2bf(float f) {
  union { float f; uint32_t u; } x; x.f = f;
  uint32_t r = (x.u + 0x7fffu + ((x.u >> 16) & 1u)) >> 16;
  return (short)(uint16_t)r;
}
__device__ __forceinline__ float bf2f(short s) {
  union { uint32_t u; float f; } x; x.u = ((uint32_t)(uint16_t)s) << 16;
  return x.f;
}

#if defined(__HIP_DEVICE_COMPILE__) && __has_builtin(__builtin_amdgcn_global_load_lds)
#define USE_GLOAD_LDS 1
#else
#define USE_GLOAD_LDS 0
#endif

#define BARRIER() asm volatile("s_barrier" ::: "memory")
#define LGKM0()                                        \
  do {                                                 \
    asm volatile("s_waitcnt lgkmcnt(0)" ::: "memory"); \
    __builtin_amdgcn_sched_barrier(0);                 \
  } while (0)
#define VMW4() asm volatile("s_waitcnt vmcnt(4)" ::: "memory")
#define VMW0() asm volatile("s_waitcnt vmcnt(0)" ::: "memory")

// ---------------------------------------------------------------------------
// 256x256 8-phase bf16 GEMM (T1+T2+T3+T4+T5). C = A[M,K] @ BT[N,K]^T + bias.
// 512 thr = 8 waves (2M x 4N), BK=64, LDS 128 KiB (2 bufs x {A 32K, B 32K}).
// st_16x32 swizzle: L ^= ((L>>9)&1)<<5 (row bit2 -> byte bit5), applied via
// pre-swizzled global source (linear global_load_lds dest) + swizzled ds_read.
// vmcnt(4) only at phases 4 and 8; raw s_barrier (no vmcnt0 drain).
// EPI: 0 f32 acc+bias | 1 f32 acc+bias+resid | 2 bf16 acc+bias | 3 bf16 silu
// ---------------------------------------------------------------------------
template <int MH>
__device__ __forceinline__ void read_a(const char* sm, int bufR, int wr, int lane,
                                       bf16x8 af[4][2]) {
#pragma unroll
  for (int m = 0; m < 4; ++m)
#pragma unroll
    for (int ks = 0; ks < 2; ++ks) {
      int row = wr * 128 + MH * 64 + m * 16 + (lane & 15);
      int L = row * 128 + ks * 64 + ((lane >> 4) << 4);
      L ^= ((L >> 9) & 1) << 5;
      af[m][ks] = *(const bf16x8*)(sm + bufR + L);
    }
}
template <int NH>
__device__ __forceinline__ void read_b(const char* sm, int bufR, int wc, int lane,
                                       bf16x8 bfv[2][2]) {
#pragma unroll
  for (int n = 0; n < 2; ++n)
#pragma unroll
    for (int ks = 0; ks < 2; ++ks) {
      int row = wc * 64 + NH * 32 + n * 16 + (lane & 15);
      int L = row * 128 + ks * 64 + ((lane >> 4) << 4);
      L ^= ((L >> 9) & 1) << 5;
      bfv[n][ks] = *(const bf16x8*)(sm + bufR + 32768 + L);
    }
}
// Stage one 16KB half-tile: rows {smh*64..+64} u {128+smh*64..+64} of a
// 256x64 bf16 operand tile. ldsbase = buf byte base (+32768 for B).
__device__ __forceinline__ void stage_half(char* sm, int ldsbase, const short* g,
                                           int ld, int smh, int w, int lane) {
#pragma unroll
  for (int i = 0; i < 2; ++i) {
    const int Lt = i * 16384 + smh * 8192 + w * 1024 + lane * 16;
    const int so = Lt ^ (((Lt >> 9) & 1) << 5);  // pre-swizzled source offset
    const short* src = g + (long)(so >> 7) * ld + ((so & 127) >> 1);
#if USE_GLOAD_LDS
    __builtin_amdgcn_global_load_lds(
        (const __attribute__((address_space(1))) void*)src,
        (__attribute__((address_space(3))) void*)(sm + ldsbase + i * 16384 +
                                                  smh * 8192 + w * 1024),
        16, 0, 0);
#else
    *(bf16x8*)(sm + ldsbase + i * 16384 + smh * 8192 + w * 1024 + lane * 16) =
        *(const bf16x8*)src;
#endif
  }
}
template <int MH, int NH>
__device__ __forceinline__ void mfma_quad(bf16x8 af[4][2], bf16x8 bfv[2][2],
                                          f32x4 acc[8][4]) {
  __builtin_amdgcn_s_setprio(1);
#pragma unroll
  for (int m = 0; m < 4; ++m)
#pragma unroll
    for (int n = 0; n < 2; ++n) {
      f32x4 a = acc[MH * 4 + m][NH * 2 + n];
      a = __builtin_amdgcn_mfma_f32_16x16x32_bf16(af[m][0], bfv[n][0], a, 0, 0, 0);
      a = __builtin_amdgcn_mfma_f32_16x16x32_bf16(af[m][1], bfv[n][1], a, 0, 0, 0);
      acc[MH * 4 + m][NH * 2 + n] = a;
    }
  __builtin_amdgcn_s_setprio(0);
}

template <int EPI>
__global__ __launch_bounds__(512, 2) void gemm256(
    const short* __restrict__ A, const short* __restrict__ BT,
    const float* __restrict__ bias, const float* __restrict__ resid,
    void* __restrict__ outp, int N, int K, int lda, int ldb, int num_m) {
  __shared__ int4 smem4[131072 / 16];
  char* sm = (char*)smem4;
  const int t = threadIdx.x;
  const int w = t >> 6, lane = t & 63;
  const int wr = w >> 2, wc = w & 3;

  // bijective XCD swizzle (m204)
  const int nwg = gridDim.x, orig = blockIdx.x;
  const int q8 = nwg >> 3, r8 = nwg & 7;
  const int xcd = orig & 7, loc = orig >> 3;
  const int wg = (xcd < r8 ? xcd * (q8 + 1) : r8 * (q8 + 1) + (xcd - r8) * q8) + loc;
  const int bm = wg % num_m, bn = wg / num_m;

  const int T = K >> 6;  // K-tiles of 64 (K is a multiple of 128)
  const short* gA = A + (long)bm * 256 * lda;
  const short* gB = BT + (long)bn * 256 * ldb;

  f32x4 acc[8][4];
#pragma unroll
  for (int i = 0; i < 8; ++i)
#pragma unroll
    for (int j = 0; j < 4; ++j) acc[i][j] = (f32x4){0.f, 0.f, 0.f, 0.f};

  const int b0 = 0, b1 = 65536;
  // ---- prologue: tile0 {A0,B0,A1,B1}, tile1 {A0,B0}; keep tile1 in flight
  stage_half(sm, b0, gA, lda, 0, w, lane);
  stage_half(sm, b0 + 32768, gB, ldb, 0, w, lane);
  stage_half(sm, b0, gA, lda, 1, w, lane);
  stage_half(sm, b0 + 32768, gB, ldb, 1, w, lane);
  stage_half(sm, b1, gA + 64, lda, 0, w, lane);
  stage_half(sm, b1 + 32768, gB + 64, ldb, 0, w, lane);
  VMW4();
  BARRIER();

  for (int t2 = 0; t2 < T; t2 += 2) {
    // clamped prefetch k-offsets (OOB tiles re-read k=0; landed data never read)
    const int k1 = (t2 + 1 < T ? t2 + 1 : 0) * 64;
    const int k2 = (t2 + 2 < T ? t2 + 2 : 0) * 64;
    const int k3 = (t2 + 3 < T ? t2 + 3 : 0) * 64;
    bf16x8 af[4][2], bfv[2][2];
    // ---- tile t2 from buf0 ----
    // P1 (mh0,nh0) | stage (t2+1)A_mh1 -> b1
    read_a<0>(sm, b0, wr, lane, af);
    read_b<0>(sm, b0, wc, lane, bfv);
    stage_half(sm, b1, gA + k1, lda, 1, w, lane);
    BARRIER(); LGKM0();
    mfma_quad<0, 0>(af, bfv, acc);
    BARRIER();
    // P2 (mh0,nh1) | stage (t2+1)B_nh1 -> b1
    read_b<1>(sm, b0, wc, lane, bfv);
    stage_half(sm, b1 + 32768, gB + k1, ldb, 1, w, lane);
    BARRIER(); LGKM0();
    mfma_quad<0, 1>(af, bfv, acc);
    BARRIER();
    // P3 (mh1,nh0) | stage (t2+2)A_mh0 -> b0
    read_a<1>(sm, b0, wr, lane, af);
    read_b<0>(sm, b0, wc, lane, bfv);
    stage_half(sm, b0, gA + k2, lda, 0, w, lane);
    BARRIER(); LGKM0();
    mfma_quad<1, 0>(af, bfv, acc);
    BARRIER();
    // P4 (mh1,nh1) | stage (t2+2)B_nh0 -> b0 | vmcnt(4)
    read_b<1>(sm, b0, wc, lane, bfv);
    stage_half(sm, b0 + 32768, gB + k2, ldb, 0, w, lane);
    BARRIER(); LGKM0();
    mfma_quad<1, 1>(af, bfv, acc);
    VMW4();
    BARRIER();
    // ---- tile t2+1 from buf1 ----
    // P5 (mh0,nh0) | stage (t2+2)A_mh1 -> b0
    read_a<0>(sm, b1, wr, lane, af);
    read_b<0>(sm, b1, wc, lane, bfv);
    stage_half(sm, b0, gA + k2, lda, 1, w, lane);
    BARRIER(); LGKM0();
    mfma_quad<0, 0>(af, bfv, acc);
    BARRIER();
    // P6 (mh0,nh1) | stage (t2+2)B_nh1 -> b0
    read_b<1>(sm, b1, wc, lane, bfv);
    stage_half(sm, b0 + 32768, gB + k2, ldb, 1, w, lane);
    BARRIER(); LGKM0();
    mfma_quad<0, 1>(af, bfv, acc);
    BARRIER();
    // P7 (mh1,nh0) | stage (t2+3)A_mh0 -> b1
    read_a<1>(sm, b1, wr, lane, af);
    read_b<0>(sm, b1, wc, lane, bfv);
    stage_half(sm, b1, gA + k3, lda, 0, w, lane);
    BARRIER(); LGKM0();
    mfma_quad<1, 0>(af, bfv, acc);
    BARRIER();
    // P8 (mh1,nh1) | stage (t2+3)B_nh0 -> b1 | vmcnt(4)
    read_b<1>(sm, b1, wc, lane, bfv);
    stage_half(sm, b1 + 32768, gB + k3, ldb, 0, w, lane);
    BARRIER(); LGKM0();
    mfma_quad<1, 1>(af, bfv, acc);
    VMW4();
    BARRIER();
  }
  VMW0();

  // ---- epilogue ----
  const int r0 = bm * 256 + wr * 128 + ((lane >> 4) << 2);
  const int c0 = bn * 256 + wc * 64 + (lane & 15);
#pragma unroll
  for (int mi = 0; mi < 8; ++mi) {
#pragma unroll
    for (int ni = 0; ni < 4; ++ni) {
      const int col = c0 + ni * 16;
      const float bv = bias ? bias[col] : 0.f;
#pragma unroll
      for (int rr = 0; rr < 4; ++rr) {
        const int row = r0 + mi * 16 + rr;
        const long idx = (long)row * N + col;
        float v = acc[mi][ni][rr] + bv;
        if (EPI == 0) {
          ((float*)outp)[idx] = v;
        } else if (EPI == 1) {
          ((float*)outp)[idx] = v + resid[idx];
        } else if (EPI == 2) {
          ((short*)outp)[idx] = f2bf(v);
        } else {
          v = v / (1.f + __expf(-v));
          ((short*)outp)[idx] = f2bf(v);
        }
      }
    }
  }
}

// ---------------------------------------------------------------------------
// Row LayerNorm over D=1024, fp32 in -> bf16 out. One block (256 thr) per row.
// ---------------------------------------------------------------------------
__global__ __launch_bounds__(256) void ln_rows(const float* __restrict__ in,
                                               const float* __restrict__ g,
                                               const float* __restrict__ bta,
                                               short* __restrict__ outp) {
  const int row = blockIdx.x;
  const int t = threadIdx.x;
  const float4 v = ((const float4*)(in + (long)row * DD))[t];
  float s = v.x + v.y + v.z + v.w;
  float ss = v.x * v.x + v.y * v.y + v.z * v.z + v.w * v.w;
#pragma unroll
  for (int off = 1; off < 64; off <<= 1) {
    s += __shfl_xor(s, off);
    ss += __shfl_xor(ss, off);
  }
  __shared__ float red[8];
  const int w = t >> 6, lane = t & 63;
  if (lane == 0) { red[w] = s; red[4 + w] = ss; }
  __syncthreads();
  s = red[0] + red[1] + red[2] + red[3];
  ss = red[4] + red[5] + red[6] + red[7];
  const float mu = s * (1.f / DD);
  const float var = ss * (1.f / DD) - mu * mu;
  const float rs = rsqrtf(var + EPSF);
  const float4 gv = ((const float4*)g)[t];
  const float4 bv = ((const float4*)bta)[t];
  short4 o;
  o.x = f2bf((v.x - mu) * rs * gv.x + bv.x);
  o.y = f2bf((v.y - mu) * rs * gv.y + bv.y);
  o.z = f2bf((v.z - mu) * rs * gv.z + bv.z);
  o.w = f2bf((v.w - mu) * rs * gv.w + bv.w);
  ((short4*)(outp + (long)row * DD))[t] = o;
}

// ---------------------------------------------------------------------------
// Transpose + fp32->bf16 convert: W[K][N] -> WT[N][K]. 64x64 tiles.
// ---------------------------------------------------------------------------
__global__ __launch_bounds__(256) void tconv(const float* __restrict__ W,
                                             short* __restrict__ WT, int K, int N) {
  __shared__ float tile[64][65];
  const int k0 = blockIdx.x * 64, n0 = blockIdx.y * 64;
  const int t = threadIdx.x;
  const int tr = t >> 6, tc = t & 63;
#pragma unroll
  for (int i = 0; i < 64; i += 4)
    tile[i + tr][tc] = W[(long)(k0 + i + tr) * N + n0 + tc];
  __syncthreads();
#pragma unroll
  for (int i = 0; i < 64; i += 4)
    WT[(long)(n0 + i + tr) * K + k0 + tc] = f2bf(tile[tc][i + tr]);
}

// ---------------------------------------------------------------------------
// ctx[b,h,d,e] = sum_m softmax_d(k[b,m,h,:])[d] * v[b,m,h,e].
// ---------------------------------------------------------------------------
__global__ __launch_bounds__(256) void ctx_kernel(const short* __restrict__ kv,
                                                  float* __restrict__ ctx) {
  const int bh = blockIdx.x;
  const int b = bh >> 4, h = bh & 15;
  const int t = threadIdx.x, g = t >> 6, lane = t & 63;
  __shared__ float ksm[4][64];
  __shared__ float vsm[4][64];
  float acc[16];
#pragma unroll
  for (int j = 0; j < 16; ++j) acc[j] = 0.f;
  const int d = t & 63;
  const int e0 = (t >> 6) * 16;
  const short* base = kv + (long)b * MTOK * 2048 + h * 64;
  for (int m0 = 0; m0 < MTOK; m0 += 4) {
    const long moff = (long)(m0 + g) * 2048;
    float kval = bf2f(base[moff + lane]);
    float vval = bf2f(base[moff + 1024 + lane]);
    float mx = kval;
#pragma unroll
    for (int off = 1; off < 64; off <<= 1) mx = fmaxf(mx, __shfl_xor(mx, off));
    float e = __expf(kval - mx);
    float sm = e;
#pragma unroll
    for (int off = 1; off < 64; off <<= 1) sm += __shfl_xor(sm, off);
    ksm[g][lane] = e / sm;
    vsm[g][lane] = vval;
    __syncthreads();
#pragma unroll
    for (int mm = 0; mm < 4; ++mm) {
      const float kd = ksm[mm][d];
#pragma unroll
      for (int j = 0; j < 16; ++j) acc[j] = fmaf(kd, vsm[mm][e0 + j], acc[j]);
    }
    __syncthreads();
  }
  float* cp = ctx + ((long)bh * 64 + d) * 64 + e0;
#pragma unroll
  for (int j = 0; j < 16; ++j) cp[j] = acc[j];
}

// ---------------------------------------------------------------------------
// Column softmax stats for q (softmax over the N axis per (b, column)).
// ---------------------------------------------------------------------------
__global__ __launch_bounds__(256) void qstat_part(const float* __restrict__ q,
                                                  float* __restrict__ pmax,
                                                  float* __restrict__ psum) {
  const int c = blockIdx.x * 256 + threadIdx.x;
  const int b = blockIdx.z, ch = blockIdx.y;
  const float* qp = q + ((long)b * NN + ch * 128) * DD + c;
  float mx = -1e30f, sm = 0.f;
  for (int r = 0; r < 128; ++r) {
    const float xv = qp[(long)r * DD];
    const float nm = fmaxf(mx, xv);
    sm = sm * __expf(mx - nm) + __expf(xv - nm);
    mx = nm;
  }
  const long idx = ((long)b * DD + c) * 32 + ch;
  pmax[idx] = mx;
  psum[idx] = sm;
}

__global__ __launch_bounds__(256) void qstat_comb(const float* __restrict__ pmax,
                                                  const float* __restrict__ psum,
                                                  float* __restrict__ cmax,
                                                  float* __restrict__ crs) {
  const int i = blockIdx.x * 256 + threadIdx.x;  // b*1024 + c
  const float* pm = pmax + (long)i * 32;
  const float* ps = psum + (long)i * 32;
  float mx = -1e30f;
#pragma unroll
  for (int ch = 0; ch < 32; ++ch) mx = fmaxf(mx, pm[ch]);
  float sm = 0.f;
#pragma unroll
  for (int ch = 0; ch < 32; ++ch) sm += ps[ch] * __expf(pm[ch] - mx);
  cmax[i] = mx;
  crs[i] = SCALE_F / sm;
}

// ---------------------------------------------------------------------------
// Fused: q_soft = exp(q-cmax)*crs (includes SCALE), out = q_soft @ ctx[b,h].
// ---------------------------------------------------------------------------
__global__ __launch_bounds__(256) void attn_apply(const float* __restrict__ q,
                                                  const float* __restrict__ ctx,
                                                  const float* __restrict__ cmax,
                                                  const float* __restrict__ crs,
                                                  short* __restrict__ outa) {
  const int b = blockIdx.z, h = blockIdx.y, n0 = blockIdx.x * 128;
  const int t = threadIdx.x, g = t >> 6, lane = t & 63;
  __shared__ float ctx_l[4096];
  __shared__ float cm[64], cs[64];
  __shared__ float qsm[4][64];
  const float* cp = ctx + (long)(b * HH + h) * 4096;
  for (int i = t; i < 4096; i += 256) ctx_l[i] = cp[i];
  if (t < 64) {
    cm[t] = cmax[(long)b * DD + h * 64 + t];
    cs[t] = crs[(long)b * DD + h * 64 + t];
  }
  __syncthreads();
  for (int i = 0; i < 32; ++i) {
    const int n = n0 + i * 4 + g;
    const long off = ((long)b * NN + n) * DD + h * 64;
    const float qv = q[off + lane];
    const float qs = __expf(qv - cm[lane]) * cs[lane];
    qsm[g][lane] = qs;  // same-wave LDS, no barrier needed
    float o = 0.f;
#pragma unroll
    for (int dd = 0; dd < 64; ++dd) o = fmaf(qsm[g][dd], ctx_l[dd * 64 + lane], o);
    outa[off + lane] = f2bf(o);
  }
}

// ---------------------------------------------------------------------------
extern "C" void kernel_launch(void* const* d_in, const int* in_sizes, int n_in,
                              void* d_out, int out_size, void* d_ws, size_t ws_size,
                              hipStream_t stream) {
  (void)in_sizes; (void)n_in; (void)out_size;
  const float* x      = (const float*)d_in[0];
  const float* wav    = (const float*)d_in[1];
  const float* ln_q_g = (const float*)d_in[2];
  const float* ln_q_b = (const float*)d_in[3];
  const float* Wq     = (const float*)d_in[4];
  const float* bq     = (const float*)d_in[5];
  const float* ln_kv_g= (const float*)d_in[6];
  const float* ln_kv_b= (const float*)d_in[7];
  const float* Wkv    = (const float*)d_in[8];
  const float* bkv    = (const float*)d_in[9];
  const float* Wo     = (const float*)d_in[10];
  const float* bo     = (const float*)d_in[11];
  const float* ln_f_g = (const float*)d_in[12];
  const float* ln_f_b = (const float*)d_in[13];
  const float* W1     = (const float*)d_in[14];
  const float* b1     = (const float*)d_in[15];
  const float* W2     = (const float*)d_in[16];
  const float* b2     = (const float*)d_in[17];
  float* outp = (float*)d_out;
  char* ws = (char*)d_ws;

  const long MR = (long)BB * NN;    // 32768 rows
  const long MKV = (long)BB * MTOK; // 8192 rows

  size_t off = 0;
  auto bump = [&](size_t bytes) {
    size_t o = off;
    off += (bytes + 255) & ~(size_t)255;
    return o;
  };
  short* WqT  = (short*)(ws + bump((size_t)DD * DD * 2));
  short* WkvT = (short*)(ws + bump((size_t)2048 * DD * 2));
  short* WoT  = (short*)(ws + bump((size_t)DD * DD * 2));
  short* W1T  = (short*)(ws + bump((size_t)4096 * DD * 2));
  short* W2T  = (short*)(ws + bump((size_t)DD * 4096 * 2));
  float* qbuf = (float*)(ws + bump((size_t)MR * DD * 4));   // later: x2 (fp32)
  short* lnbuf= (short*)(ws + bump((size_t)MR * DD * 2));   // xq_ln, later x2_ln
  float* ctx  = (float*)(ws + bump((size_t)BB * HH * 64 * 64 * 4));
  float* pmax = (float*)(ws + bump((size_t)BB * DD * 32 * 4));
  float* psum = (float*)(ws + bump((size_t)BB * DD * 32 * 4));
  float* cmax = (float*)(ws + bump((size_t)BB * DD * 4));
  float* crs  = (float*)(ws + bump((size_t)BB * DD * 4));
  const size_t dyn0 = off;
  short* wvln  = (short*)(ws + dyn0);
  short* kvbuf = (short*)(ws + dyn0 + (size_t)MKV * DD * 2);
  short* oattn = (short*)(ws + dyn0);  // reuses wvln+kv region (dead by then)
  short* hbuf  = (short*)(ws + dyn0);  // MLP phase (oattn dead by then)

  size_t avail = ws_size > dyn0 ? ws_size - dyn0 : 0;
  int CS = 4096;
  while (CS > 256 && (size_t)MR * CS * 2 > avail) CS >>= 1;

  const int nm = (int)(MR / 256);    // 128
  const int nmkv = (int)(MKV / 256); // 32

  // 1) weight convert+transpose to bf16 [N][K]
  tconv<<<dim3(DD / 64, DD / 64), 256, 0, stream>>>(Wq, WqT, DD, DD);
  tconv<<<dim3(DD / 64, 2048 / 64), 256, 0, stream>>>(Wkv, WkvT, DD, 2048);
  tconv<<<dim3(DD / 64, DD / 64), 256, 0, stream>>>(Wo, WoT, DD, DD);
  tconv<<<dim3(DD / 64, 4096 / 64), 256, 0, stream>>>(W1, W1T, DD, 4096);
  tconv<<<dim3(4096 / 64, DD / 64), 256, 0, stream>>>(W2, W2T, 4096, DD);

  // 2) LayerNorms -> bf16
  ln_rows<<<dim3((unsigned)MR), 256, 0, stream>>>(x, ln_q_g, ln_q_b, lnbuf);
  ln_rows<<<dim3((unsigned)MKV), 256, 0, stream>>>(wav, ln_kv_g, ln_kv_b, wvln);

  // 3) q = LN(x) @ Wq + bq   (fp32 out, needed for column softmax)
  gemm256<0><<<dim3((unsigned)(nm * (DD / 256))), 512, 0, stream>>>(
      lnbuf, WqT, bq, nullptr, qbuf, DD, DD, DD, DD, nm);
  // 4) kv = LN(wav) @ Wkv + bkv  (bf16 out)
  gemm256<2><<<dim3((unsigned)(nmkv * (2048 / 256))), 512, 0, stream>>>(
      wvln, WkvT, bkv, nullptr, kvbuf, 2048, DD, DD, DD, nmkv);
  // 5) context per (b,h)
  ctx_kernel<<<dim3(BB * HH), 256, 0, stream>>>(kvbuf, ctx);
  // 6) q column-softmax stats
  qstat_part<<<dim3(DD / 256, 32, BB), 256, 0, stream>>>(qbuf, pmax, psum);
  qstat_comb<<<dim3(BB * DD / 256), 256, 0, stream>>>(pmax, psum, cmax, crs);
  // 7) softmax-apply + per-head 64x64 matmul -> out_attn (bf16, overwrites kv)
  attn_apply<<<dim3(NN / 128, HH, BB), 256, 0, stream>>>(qbuf, ctx, cmax, crs, oattn);
  // 8) x2 = out_attn @ Wo + bo + x   (fp32, overwrites q)
  gemm256<1><<<dim3((unsigned)(nm * (DD / 256))), 512, 0, stream>>>(
      oattn, WoT, bo, x, qbuf, DD, DD, DD, DD, nm);
  float* x2 = qbuf;
  // 9) LN_f(x2) -> bf16
  ln_rows<<<dim3((unsigned)MR), 256, 0, stream>>>(x2, ln_f_g, ln_f_b, lnbuf);
  // 10) MLP: h = silu(x2ln @ W1 + b1); out = x2 + h @ W2 + b2
  for (int c0 = 0; c0 < 4096; c0 += CS) {
    gemm256<3><<<dim3((unsigned)(nm * (CS / 256))), 512, 0, stream>>>(
        lnbuf, W1T + (long)c0 * DD, b1 + c0, nullptr, hbuf, CS, DD, DD, DD, nm);
    gemm256<1><<<dim3((unsigned)(nm * (DD / 256))), 512, 0, stream>>>(
        hbuf, W2T + c0, (c0 == 0) ? b2 : nullptr,
        (c0 == 0) ? (const float*)x2 : (const float*)outp, outp, DD, CS, CS, 4096, nm);
  }
}

// Round 3
// 1352.004 us; speedup vs baseline: 1.3094x; 1.0364x over previous
//
#include <hip/hip_runtime.h>
#include <stdint.h>
#include <stddef.h>

#define BB 8
#define NN 4096
#define MTOK 1024
#define DD 1024
#define HH 16
#define EPSF 1e-6f
static const float SCALE_F = 0.125f; // HD^-0.5, HD=64

typedef __attribute__((ext_vector_type(4))) float f32x4;
typedef __attribute__((ext_vector_type(8))) short bf16x8;

__device__ __forceinline__ short f2bf(float f) {
  union { float f; uint32_t u; } x; x.f = f;
  uint32_t r = (x.u + 0x7fffu + ((x.u >> 16) & 1u)) >> 16;
  return (short)(uint16_t)r;
}
__device__ __forceinline__ float bf2f(short s) {
  union { uint32_t u; float f; } x; x.u = ((uint32_t)(uint16_t)s) << 16;
  return x.f;
}

#if defined(__HIP_DEVICE_COMPILE__) && __has_builtin(__builtin_amdgcn_global_load_lds)
#define USE_GLOAD_LDS 1
#else
#define USE_GLOAD_LDS 0
#endif

#define BARRIER() asm volatile("s_barrier" ::: "memory")
#define LGKM0()                                        \
  do {                                                 \
    asm volatile("s_waitcnt lgkmcnt(0)" ::: "memory"); \
    __builtin_amdgcn_sched_barrier(0);                 \
  } while (0)
#define VMW4() asm volatile("s_waitcnt vmcnt(4)" ::: "memory")
#define VMW0() asm volatile("s_waitcnt vmcnt(0)" ::: "memory")

// Swizzle: XOR row bits 0-2 (byte-offset bits 7-9) into 16B-slot bits 4-6.
// Involution; spreads 16 same-column lanes across all 32 banks (2-way residual).
__device__ __forceinline__ int swz(int L) { return L ^ (((L >> 7) & 7) << 4); }

// ---------------------------------------------------------------------------
// 256x256 8-phase bf16 GEMM (T1+T2+T3+T4+T5). C = A[M,K] @ BT[N,K]^T + bias.
// 512 thr = 8 waves (2M x 4N), BK=64, LDS 128 KiB (2 bufs x {A 32K, B 32K}).
// (row&7)<<4 XOR swizzle applied via pre-swizzled global source (linear
// global_load_lds dest) + swizzled ds_read (same involution both sides).
// vmcnt(4) only at phases 4 and 8; raw s_barrier (no vmcnt0 drain).
// EPI: 0 f32 acc+bias | 1 f32 acc+bias+resid | 2 bf16 acc+bias | 3 bf16 silu
// ---------------------------------------------------------------------------
template <int MH>
__device__ __forceinline__ void read_a(const char* sm, int bufR, int wr, int lane,
                                       bf16x8 af[4][2]) {
#pragma unroll
  for (int m = 0; m < 4; ++m)
#pragma unroll
    for (int ks = 0; ks < 2; ++ks) {
      int row = wr * 128 + MH * 64 + m * 16 + (lane & 15);
      int L = swz(row * 128 + ks * 64 + ((lane >> 4) << 4));
      af[m][ks] = *(const bf16x8*)(sm + bufR + L);
    }
}
template <int NH>
__device__ __forceinline__ void read_b(const char* sm, int bufR, int wc, int lane,
                                       bf16x8 bfv[2][2]) {
#pragma unroll
  for (int n = 0; n < 2; ++n)
#pragma unroll
    for (int ks = 0; ks < 2; ++ks) {
      int row = wc * 64 + NH * 32 + n * 16 + (lane & 15);
      int L = swz(row * 128 + ks * 64 + ((lane >> 4) << 4));
      bfv[n][ks] = *(const bf16x8*)(sm + bufR + 32768 + L);
    }
}
// Stage one 16KB half-tile: rows {smh*64..+64} u {128+smh*64..+64} of a
// 256x64 bf16 operand tile. ldsbase = buf byte base (+32768 for B).
__device__ __forceinline__ void stage_half(char* sm, int ldsbase, const short* g,
                                           int ld, int smh, int w, int lane) {
#pragma unroll
  for (int i = 0; i < 2; ++i) {
    const int Lt = i * 16384 + smh * 8192 + w * 1024 + lane * 16;
    const int so = swz(Lt);  // pre-swizzled source offset (same involution)
    const short* src = g + (long)(so >> 7) * ld + ((so & 127) >> 1);
#if USE_GLOAD_LDS
    __builtin_amdgcn_global_load_lds(
        (const __attribute__((address_space(1))) void*)src,
        (__attribute__((address_space(3))) void*)(sm + ldsbase + i * 16384 +
                                                  smh * 8192 + w * 1024),
        16, 0, 0);
#else
    *(bf16x8*)(sm + ldsbase + i * 16384 + smh * 8192 + w * 1024 + lane * 16) =
        *(const bf16x8*)src;
#endif
  }
}
template <int MH, int NH>
__device__ __forceinline__ void mfma_quad(bf16x8 af[4][2], bf16x8 bfv[2][2],
                                          f32x4 acc[8][4]) {
  __builtin_amdgcn_s_setprio(1);
#pragma unroll
  for (int m = 0; m < 4; ++m)
#pragma unroll
    for (int n = 0; n < 2; ++n) {
      f32x4 a = acc[MH * 4 + m][NH * 2 + n];
      a = __builtin_amdgcn_mfma_f32_16x16x32_bf16(af[m][0], bfv[n][0], a, 0, 0, 0);
      a = __builtin_amdgcn_mfma_f32_16x16x32_bf16(af[m][1], bfv[n][1], a, 0, 0, 0);
      acc[MH * 4 + m][NH * 2 + n] = a;
    }
  __builtin_amdgcn_s_setprio(0);
}

template <int EPI>
__global__ __launch_bounds__(512, 2) void gemm256(
    const short* __restrict__ A, const short* __restrict__ BT,
    const float* __restrict__ bias, const float* __restrict__ resid,
    void* __restrict__ outp, int N, int K, int lda, int ldb, int num_m) {
  __shared__ int4 smem4[131072 / 16];
  char* sm = (char*)smem4;
  const int t = threadIdx.x;
  const int w = t >> 6, lane = t & 63;
  const int wr = w >> 2, wc = w & 3;

  // bijective XCD swizzle (m204)
  const int nwg = gridDim.x, orig = blockIdx.x;
  const int q8 = nwg >> 3, r8 = nwg & 7;
  const int xcd = orig & 7, loc = orig >> 3;
  const int wg = (xcd < r8 ? xcd * (q8 + 1) : r8 * (q8 + 1) + (xcd - r8) * q8) + loc;
  const int bm = wg % num_m, bn = wg / num_m;

  const int T = K >> 6;  // K-tiles of 64 (K is a multiple of 128)
  const short* gA = A + (long)bm * 256 * lda;
  const short* gB = BT + (long)bn * 256 * ldb;

  f32x4 acc[8][4];
#pragma unroll
  for (int i = 0; i < 8; ++i)
#pragma unroll
    for (int j = 0; j < 4; ++j) acc[i][j] = (f32x4){0.f, 0.f, 0.f, 0.f};

  const int b0 = 0, b1 = 65536;
  // ---- prologue: tile0 {A0,B0,A1,B1}, tile1 {A0,B0}; keep tile1 in flight
  stage_half(sm, b0, gA, lda, 0, w, lane);
  stage_half(sm, b0 + 32768, gB, ldb, 0, w, lane);
  stage_half(sm, b0, gA, lda, 1, w, lane);
  stage_half(sm, b0 + 32768, gB, ldb, 1, w, lane);
  stage_half(sm, b1, gA + 64, lda, 0, w, lane);
  stage_half(sm, b1 + 32768, gB + 64, ldb, 0, w, lane);
  VMW4();
  BARRIER();

  for (int t2 = 0; t2 < T; t2 += 2) {
    // clamped prefetch k-offsets (OOB tiles re-read k=0; landed data never read)
    const int k1 = (t2 + 1 < T ? t2 + 1 : 0) * 64;
    const int k2 = (t2 + 2 < T ? t2 + 2 : 0) * 64;
    const int k3 = (t2 + 3 < T ? t2 + 3 : 0) * 64;
    bf16x8 af[4][2], bfv[2][2];
    // ---- tile t2 from buf0 ----
    // P1 (mh0,nh0) | stage (t2+1)A_mh1 -> b1
    read_a<0>(sm, b0, wr, lane, af);
    read_b<0>(sm, b0, wc, lane, bfv);
    stage_half(sm, b1, gA + k1, lda, 1, w, lane);
    BARRIER(); LGKM0();
    mfma_quad<0, 0>(af, bfv, acc);
    BARRIER();
    // P2 (mh0,nh1) | stage (t2+1)B_nh1 -> b1
    read_b<1>(sm, b0, wc, lane, bfv);
    stage_half(sm, b1 + 32768, gB + k1, ldb, 1, w, lane);
    BARRIER(); LGKM0();
    mfma_quad<0, 1>(af, bfv, acc);
    BARRIER();
    // P3 (mh1,nh0) | stage (t2+2)A_mh0 -> b0
    read_a<1>(sm, b0, wr, lane, af);
    read_b<0>(sm, b0, wc, lane, bfv);
    stage_half(sm, b0, gA + k2, lda, 0, w, lane);
    BARRIER(); LGKM0();
    mfma_quad<1, 0>(af, bfv, acc);
    BARRIER();
    // P4 (mh1,nh1) | stage (t2+2)B_nh0 -> b0 | vmcnt(4)
    read_b<1>(sm, b0, wc, lane, bfv);
    stage_half(sm, b0 + 32768, gB + k2, ldb, 0, w, lane);
    BARRIER(); LGKM0();
    mfma_quad<1, 1>(af, bfv, acc);
    VMW4();
    BARRIER();
    // ---- tile t2+1 from buf1 ----
    // P5 (mh0,nh0) | stage (t2+2)A_mh1 -> b0
    read_a<0>(sm, b1, wr, lane, af);
    read_b<0>(sm, b1, wc, lane, bfv);
    stage_half(sm, b0, gA + k2, lda, 1, w, lane);
    BARRIER(); LGKM0();
    mfma_quad<0, 0>(af, bfv, acc);
    BARRIER();
    // P6 (mh0,nh1) | stage (t2+2)B_nh1 -> b0
    read_b<1>(sm, b1, wc, lane, bfv);
    stage_half(sm, b0 + 32768, gB + k2, ldb, 1, w, lane);
    BARRIER(); LGKM0();
    mfma_quad<0, 1>(af, bfv, acc);
    BARRIER();
    // P7 (mh1,nh0) | stage (t2+3)A_mh0 -> b1
    read_a<1>(sm, b1, wr, lane, af);
    read_b<0>(sm, b1, wc, lane, bfv);
    stage_half(sm, b1, gA + k3, lda, 0, w, lane);
    BARRIER(); LGKM0();
    mfma_quad<1, 0>(af, bfv, acc);
    BARRIER();
    // P8 (mh1,nh1) | stage (t2+3)B_nh0 -> b1 | vmcnt(4)
    read_b<1>(sm, b1, wc, lane, bfv);
    stage_half(sm, b1 + 32768, gB + k3, ldb, 0, w, lane);
    BARRIER(); LGKM0();
    mfma_quad<1, 1>(af, bfv, acc);
    VMW4();
    BARRIER();
  }
  VMW0();

  // ---- epilogue ----
  const int r0 = bm * 256 + wr * 128 + ((lane >> 4) << 2);
  const int c0 = bn * 256 + wc * 64 + (lane & 15);
#pragma unroll
  for (int mi = 0; mi < 8; ++mi) {
#pragma unroll
    for (int ni = 0; ni < 4; ++ni) {
      const int col = c0 + ni * 16;
      const float bv = bias ? bias[col] : 0.f;
#pragma unroll
      for (int rr = 0; rr < 4; ++rr) {
        const int row = r0 + mi * 16 + rr;
        const long idx = (long)row * N + col;
        float v = acc[mi][ni][rr] + bv;
        if (EPI == 0) {
          ((float*)outp)[idx] = v;
        } else if (EPI == 1) {
          ((float*)outp)[idx] = v + resid[idx];
        } else if (EPI == 2) {
          ((short*)outp)[idx] = f2bf(v);
        } else {
          v = v / (1.f + __expf(-v));
          ((short*)outp)[idx] = f2bf(v);
        }
      }
    }
  }
}

// ---------------------------------------------------------------------------
// Row LayerNorm over D=1024, fp32 in -> bf16 out. One block (256 thr) per row.
// ---------------------------------------------------------------------------
__global__ __launch_bounds__(256) void ln_rows(const float* __restrict__ in,
                                               const float* __restrict__ g,
                                               const float* __restrict__ bta,
                                               short* __restrict__ outp) {
  const int row = blockIdx.x;
  const int t = threadIdx.x;
  const float4 v = ((const float4*)(in + (long)row * DD))[t];
  float s = v.x + v.y + v.z + v.w;
  float ss = v.x * v.x + v.y * v.y + v.z * v.z + v.w * v.w;
#pragma unroll
  for (int off = 1; off < 64; off <<= 1) {
    s += __shfl_xor(s, off);
    ss += __shfl_xor(ss, off);
  }
  __shared__ float red[8];
  const int w = t >> 6, lane = t & 63;
  if (lane == 0) { red[w] = s; red[4 + w] = ss; }
  __syncthreads();
  s = red[0] + red[1] + red[2] + red[3];
  ss = red[4] + red[5] + red[6] + red[7];
  const float mu = s * (1.f / DD);
  const float var = ss * (1.f / DD) - mu * mu;
  const float rs = rsqrtf(var + EPSF);
  const float4 gv = ((const float4*)g)[t];
  const float4 bv = ((const float4*)bta)[t];
  short4 o;
  o.x = f2bf((v.x - mu) * rs * gv.x + bv.x);
  o.y = f2bf((v.y - mu) * rs * gv.y + bv.y);
  o.z = f2bf((v.z - mu) * rs * gv.z + bv.z);
  o.w = f2bf((v.w - mu) * rs * gv.w + bv.w);
  ((short4*)(outp + (long)row * DD))[t] = o;
}

// ---------------------------------------------------------------------------
// Transpose + fp32->bf16 convert: W[K][N] -> WT[N][K]. 64x64 tiles.
// ---------------------------------------------------------------------------
__global__ __launch_bounds__(256) void tconv(const float* __restrict__ W,
                                             short* __restrict__ WT, int K, int N) {
  __shared__ float tile[64][65];
  const int k0 = blockIdx.x * 64, n0 = blockIdx.y * 64;
  const int t = threadIdx.x;
  const int tr = t >> 6, tc = t & 63;
#pragma unroll
  for (int i = 0; i < 64; i += 4)
    tile[i + tr][tc] = W[(long)(k0 + i + tr) * N + n0 + tc];
  __syncthreads();
#pragma unroll
  for (int i = 0; i < 64; i += 4)
    WT[(long)(n0 + i + tr) * K + k0 + tc] = f2bf(tile[tc][i + tr]);
}

// ---------------------------------------------------------------------------
// ctx[b,h,d,e] = sum_m softmax_d(k[b,m,h,:])[d] * v[b,m,h,e].
// ---------------------------------------------------------------------------
__global__ __launch_bounds__(256) void ctx_kernel(const short* __restrict__ kv,
                                                  float* __restrict__ ctx) {
  const int bh = blockIdx.x;
  const int b = bh >> 4, h = bh & 15;
  const int t = threadIdx.x, g = t >> 6, lane = t & 63;
  __shared__ float ksm[4][64];
  __shared__ float vsm[4][64];
  float acc[16];
#pragma unroll
  for (int j = 0; j < 16; ++j) acc[j] = 0.f;
  const int d = t & 63;
  const int e0 = (t >> 6) * 16;
  const short* base = kv + (long)b * MTOK * 2048 + h * 64;
  for (int m0 = 0; m0 < MTOK; m0 += 4) {
    const long moff = (long)(m0 + g) * 2048;
    float kval = bf2f(base[moff + lane]);
    float vval = bf2f(base[moff + 1024 + lane]);
    float mx = kval;
#pragma unroll
    for (int off = 1; off < 64; off <<= 1) mx = fmaxf(mx, __shfl_xor(mx, off));
    float e = __expf(kval - mx);
    float sm = e;
#pragma unroll
    for (int off = 1; off < 64; off <<= 1) sm += __shfl_xor(sm, off);
    ksm[g][lane] = e / sm;
    vsm[g][lane] = vval;
    __syncthreads();
#pragma unroll
    for (int mm = 0; mm < 4; ++mm) {
      const float kd = ksm[mm][d];
#pragma unroll
      for (int j = 0; j < 16; ++j) acc[j] = fmaf(kd, vsm[mm][e0 + j], acc[j]);
    }
    __syncthreads();
  }
  float* cp = ctx + ((long)bh * 64 + d) * 64 + e0;
#pragma unroll
  for (int j = 0; j < 16; ++j) cp[j] = acc[j];
}

// ---------------------------------------------------------------------------
// Column softmax stats for q (softmax over the N axis per (b, column)).
// ---------------------------------------------------------------------------
__global__ __launch_bounds__(256) void qstat_part(const float* __restrict__ q,
                                                  float* __restrict__ pmax,
                                                  float* __restrict__ psum) {
  const int c = blockIdx.x * 256 + threadIdx.x;
  const int b = blockIdx.z, ch = blockIdx.y;
  const float* qp = q + ((long)b * NN + ch * 128) * DD + c;
  float mx = -1e30f, sm = 0.f;
  for (int r = 0; r < 128; ++r) {
    const float xv = qp[(long)r * DD];
    const float nm = fmaxf(mx, xv);
    sm = sm * __expf(mx - nm) + __expf(xv - nm);
    mx = nm;
  }
  const long idx = ((long)b * DD + c) * 32 + ch;
  pmax[idx] = mx;
  psum[idx] = sm;
}

__global__ __launch_bounds__(256) void qstat_comb(const float* __restrict__ pmax,
                                                  const float* __restrict__ psum,
                                                  float* __restrict__ cmax,
                                                  float* __restrict__ crs) {
  const int i = blockIdx.x * 256 + threadIdx.x;  // b*1024 + c
  const float* pm = pmax + (long)i * 32;
  const float* ps = psum + (long)i * 32;
  float mx = -1e30f;
#pragma unroll
  for (int ch = 0; ch < 32; ++ch) mx = fmaxf(mx, pm[ch]);
  float sm = 0.f;
#pragma unroll
  for (int ch = 0; ch < 32; ++ch) sm += ps[ch] * __expf(pm[ch] - mx);
  cmax[i] = mx;
  crs[i] = SCALE_F / sm;
}

// ---------------------------------------------------------------------------
// Fused: q_soft = exp(q-cmax)*crs (includes SCALE), out = q_soft @ ctx[b,h].
// ---------------------------------------------------------------------------
__global__ __launch_bounds__(256) void attn_apply(const float* __restrict__ q,
                                                  const float* __restrict__ ctx,
                                                  const float* __restrict__ cmax,
                                                  const float* __restrict__ crs,
                                                  short* __restrict__ outa) {
  const int b = blockIdx.z, h = blockIdx.y, n0 = blockIdx.x * 128;
  const int t = threadIdx.x, g = t >> 6, lane = t & 63;
  __shared__ float ctx_l[4096];
  __shared__ float cm[64], cs[64];
  __shared__ float qsm[4][64];
  const float* cp = ctx + (long)(b * HH + h) * 4096;
  for (int i = t; i < 4096; i += 256) ctx_l[i] = cp[i];
  if (t < 64) {
    cm[t] = cmax[(long)b * DD + h * 64 + t];
    cs[t] = crs[(long)b * DD + h * 64 + t];
  }
  __syncthreads();
  for (int i = 0; i < 32; ++i) {
    const int n = n0 + i * 4 + g;
    const long off = ((long)b * NN + n) * DD + h * 64;
    const float qv = q[off + lane];
    const float qs = __expf(qv - cm[lane]) * cs[lane];
    qsm[g][lane] = qs;  // same-wave LDS, no barrier needed
    float o = 0.f;
#pragma unroll
    for (int dd = 0; dd < 64; ++dd) o = fmaf(qsm[g][dd], ctx_l[dd * 64 + lane], o);
    outa[off + lane] = f2bf(o);
  }
}

// ---------------------------------------------------------------------------
extern "C" void kernel_launch(void* const* d_in, const int* in_sizes, int n_in,
                              void* d_out, int out_size, void* d_ws, size_t ws_size,
                              hipStream_t stream) {
  (void)in_sizes; (void)n_in; (void)out_size;
  const float* x      = (const float*)d_in[0];
  const float* wav    = (const float*)d_in[1];
  const float* ln_q_g = (const float*)d_in[2];
  const float* ln_q_b = (const float*)d_in[3];
  const float* Wq     = (const float*)d_in[4];
  const float* bq     = (const float*)d_in[5];
  const float* ln_kv_g= (const float*)d_in[6];
  const float* ln_kv_b= (const float*)d_in[7];
  const float* Wkv    = (const float*)d_in[8];
  const float* bkv    = (const float*)d_in[9];
  const float* Wo     = (const float*)d_in[10];
  const float* bo     = (const float*)d_in[11];
  const float* ln_f_g = (const float*)d_in[12];
  const float* ln_f_b = (const float*)d_in[13];
  const float* W1     = (const float*)d_in[14];
  const float* b1     = (const float*)d_in[15];
  const float* W2     = (const float*)d_in[16];
  const float* b2     = (const float*)d_in[17];
  float* outp = (float*)d_out;
  char* ws = (char*)d_ws;

  const long MR = (long)BB * NN;    // 32768 rows
  const long MKV = (long)BB * MTOK; // 8192 rows

  size_t off = 0;
  auto bump = [&](size_t bytes) {
    size_t o = off;
    off += (bytes + 255) & ~(size_t)255;
    return o;
  };
  short* WqT  = (short*)(ws + bump((size_t)DD * DD * 2));
  short* WkvT = (short*)(ws + bump((size_t)2048 * DD * 2));
  short* WoT  = (short*)(ws + bump((size_t)DD * DD * 2));
  short* W1T  = (short*)(ws + bump((size_t)4096 * DD * 2));
  short* W2T  = (short*)(ws + bump((size_t)DD * 4096 * 2));
  float* qbuf = (float*)(ws + bump((size_t)MR * DD * 4));   // later: x2 (fp32)
  short* lnbuf= (short*)(ws + bump((size_t)MR * DD * 2));   // xq_ln, later x2_ln
  float* ctx  = (float*)(ws + bump((size_t)BB * HH * 64 * 64 * 4));
  float* pmax = (float*)(ws + bump((size_t)BB * DD * 32 * 4));
  float* psum = (float*)(ws + bump((size_t)BB * DD * 32 * 4));
  float* cmax = (float*)(ws + bump((size_t)BB * DD * 4));
  float* crs  = (float*)(ws + bump((size_t)BB * DD * 4));
  const size_t dyn0 = off;
  short* wvln  = (short*)(ws + dyn0);
  short* kvbuf = (short*)(ws + dyn0 + (size_t)MKV * DD * 2);
  short* oattn = (short*)(ws + dyn0);  // reuses wvln+kv region (dead by then)
  short* hbuf  = (short*)(ws + dyn0);  // MLP phase (oattn dead by then)

  size_t avail = ws_size > dyn0 ? ws_size - dyn0 : 0;
  int CS = 4096;
  while (CS > 256 && (size_t)MR * CS * 2 > avail) CS >>= 1;

  const int nm = (int)(MR / 256);    // 128
  const int nmkv = (int)(MKV / 256); // 32

  // 1) weight convert+transpose to bf16 [N][K]
  tconv<<<dim3(DD / 64, DD / 64), 256, 0, stream>>>(Wq, WqT, DD, DD);
  tconv<<<dim3(DD / 64, 2048 / 64), 256, 0, stream>>>(Wkv, WkvT, DD, 2048);
  tconv<<<dim3(DD / 64, DD / 64), 256, 0, stream>>>(Wo, WoT, DD, DD);
  tconv<<<dim3(DD / 64, 4096 / 64), 256, 0, stream>>>(W1, W1T, DD, 4096);
  tconv<<<dim3(4096 / 64, DD / 64), 256, 0, stream>>>(W2, W2T, 4096, DD);

  // 2) LayerNorms -> bf16
  ln_rows<<<dim3((unsigned)MR), 256, 0, stream>>>(x, ln_q_g, ln_q_b, lnbuf);
  ln_rows<<<dim3((unsigned)MKV), 256, 0, stream>>>(wav, ln_kv_g, ln_kv_b, wvln);

  // 3) q = LN(x) @ Wq + bq   (fp32 out, needed for column softmax)
  gemm256<0><<<dim3((unsigned)(nm * (DD / 256))), 512, 0, stream>>>(
      lnbuf, WqT, bq, nullptr, qbuf, DD, DD, DD, DD, nm);
  // 4) kv = LN(wav) @ Wkv + bkv  (bf16 out)
  gemm256<2><<<dim3((unsigned)(nmkv * (2048 / 256))), 512, 0, stream>>>(
      wvln, WkvT, bkv, nullptr, kvbuf, 2048, DD, DD, DD, nmkv);
  // 5) context per (b,h)
  ctx_kernel<<<dim3(BB * HH), 256, 0, stream>>>(kvbuf, ctx);
  // 6) q column-softmax stats
  qstat_part<<<dim3(DD / 256, 32, BB), 256, 0, stream>>>(qbuf, pmax, psum);
  qstat_comb<<<dim3(BB * DD / 256), 256, 0, stream>>>(pmax, psum, cmax, crs);
  // 7) softmax-apply + per-head 64x64 matmul -> out_attn (bf16, overwrites kv)
  attn_apply<<<dim3(NN / 128, HH, BB), 256, 0, stream>>>(qbuf, ctx, cmax, crs, oattn);
  // 8) x2 = out_attn @ Wo + bo + x   (fp32, overwrites q)
  gemm256<1><<<dim3((unsigned)(nm * (DD / 256))), 512, 0, stream>>>(
      oattn, WoT, bo, x, qbuf, DD, DD, DD, DD, nm);
  float* x2 = qbuf;
  // 9) LN_f(x2) -> bf16
  ln_rows<<<dim3((unsigned)MR), 256, 0, stream>>>(x2, ln_f_g, ln_f_b, lnbuf);
  // 10) MLP: h = silu(x2ln @ W1 + b1); out = x2 + h @ W2 + b2
  for (int c0 = 0; c0 < 4096; c0 += CS) {
    gemm256<3><<<dim3((unsigned)(nm * (CS / 256))), 512, 0, stream>>>(
        lnbuf, W1T + (long)c0 * DD, b1 + c0, nullptr, hbuf, CS, DD, DD, DD, nm);
    gemm256<1><<<dim3((unsigned)(nm * (DD / 256))), 512, 0, stream>>>(
        hbuf, W2T + c0, (c0 == 0) ? b2 : nullptr,
        (c0 == 0) ? (const float*)x2 : (const float*)outp, outp, DD, CS, CS, 4096, nm);
  }
}

// Round 4
// 1347.341 us; speedup vs baseline: 1.3139x; 1.0035x over previous
//
#include <hip/hip_runtime.h>
#include <stdint.h>
#include <stddef.h>

#define BB 8
#define NN 4096
#define MTOK 1024
#define DD 1024
#define HH 16
#define EPSF 1e-6f
static const float SCALE_F = 0.125f; // HD^-0.5, HD=64

typedef __attribute__((ext_vector_type(4))) float f32x4;
typedef __attribute__((ext_vector_type(8))) short bf16x8;

__device__ __forceinline__ short f2bf(float f) {
  union { float f; uint32_t u; } x; x.f = f;
  uint32_t r = (x.u + 0x7fffu + ((x.u >> 16) & 1u)) >> 16;
  return (short)(uint16_t)r;
}
__device__ __forceinline__ float bf2f(short s) {
  union { uint32_t u; float f; } x; x.u = ((uint32_t)(uint16_t)s) << 16;
  return x.f;
}

#if defined(__HIP_DEVICE_COMPILE__) && __has_builtin(__builtin_amdgcn_global_load_lds)
#define USE_GLOAD_LDS 1
#else
#define USE_GLOAD_LDS 0
#endif

#define BAR() __builtin_amdgcn_s_barrier()
#if USE_GLOAD_LDS
#define VMW6() asm volatile("s_waitcnt vmcnt(6)" ::: "memory")
#define VMW8() asm volatile("s_waitcnt vmcnt(8)" ::: "memory")
#else
// fallback staging uses plain LDS stores -> must drain lgkm before barriers
#define VMW6() asm volatile("s_waitcnt vmcnt(0) lgkmcnt(0)" ::: "memory")
#define VMW8() asm volatile("s_waitcnt vmcnt(0) lgkmcnt(0)" ::: "memory")
#endif
#define VMW0() asm volatile("s_waitcnt vmcnt(0)" ::: "memory")

// ---------------------------------------------------------------------------
// 256x256 8-phase bf16 GEMM, read-ahead pipelined (T1+T2+T3+T4+T5).
// C = A[M,K] @ BT[N,K]^T + bias. 512 thr = 8 waves (2M x 4N), BK=64,
// LDS 128 KiB (2 bufs x {A 32K, B 32K}). Swizzle: byte ^= ((byte>>7)&7)<<4,
// pre-applied on global stage source (linear global_load_lds dest) and on
// precomputed ds_read base pointers (ks=1 base = base^64; all other frag
// offsets live in bits >=11, carry-free pure adds).
// Schedule per phase: [ds_reads for a FUTURE quadrant][stage 1 half-tile]
// [vmcnt(6)][s_barrier][16 MFMA of the CURRENT quadrant]. Compiler emits
// counted lgkm waits, so this phase's reads drain under the MFMA cluster.
// Stage->read-issue gap >= 4 phases; every read covered by the vmcnt(6)
// 3 phases earlier; stages land >=3 barriers after the region's last read.
// EPI: 0 f32 acc+bias | 1 f32 acc+bias+resid | 2 bf16 acc+bias | 3 bf16 silu
// ---------------------------------------------------------------------------
__device__ __forceinline__ bf16x8 ldsld(const char* p, int off) {
  return *(const bf16x8*)(p + off);
}
template <int MH, int MLO>
__device__ __forceinline__ void rdA2(const char* k0, const char* k1, bf16x8 a[4][2]) {
#pragma unroll
  for (int m = MLO * 2; m < MLO * 2 + 2; ++m) {
    a[m][0] = ldsld(k0, MH * 8192 + m * 2048);
    a[m][1] = ldsld(k1, MH * 8192 + m * 2048);
  }
}
template <int NH>
__device__ __forceinline__ void rdB2(const char* k0, const char* k1, bf16x8 b[2][2]) {
#pragma unroll
  for (int n = 0; n < 2; ++n) {
    b[n][0] = ldsld(k0, NH * 4096 + n * 2048);
    b[n][1] = ldsld(k1, NH * 4096 + n * 2048);
  }
}
// Stage one 16KB half-tile (rows smh*64..+64 and 128+smh*64..+64 of a 256x64
// operand tile). pg already encodes the per-thread swizzled (row,col).
__device__ __forceinline__ void stg(char* smc, int ldsbase, const short* pg,
                                    int ld, int smh, int k, int w) {
#pragma unroll
  for (int i = 0; i < 2; ++i) {
    const short* src = pg + (long)(smh * 64 + i * 128) * ld + k;
#if USE_GLOAD_LDS
    __builtin_amdgcn_global_load_lds(
        (const __attribute__((address_space(1))) void*)src,
        (__attribute__((address_space(3))) void*)(smc + ldsbase + i * 16384 +
                                                  smh * 8192 + w * 1024),
        16, 0, 0);
#else
    *(bf16x8*)(smc + ldsbase + i * 16384 + smh * 8192 + w * 1024 +
               (int)(threadIdx.x & 63) * 16) = *(const bf16x8*)src;
#endif
  }
}
template <int MH, int NH>
__device__ __forceinline__ void mq(const bf16x8 a[4][2], const bf16x8 b[2][2],
                                   f32x4 acc[8][4]) {
  __builtin_amdgcn_s_setprio(1);
#pragma unroll
  for (int m = 0; m < 4; ++m)
#pragma unroll
    for (int n = 0; n < 2; ++n) {
      f32x4 c = acc[MH * 4 + m][NH * 2 + n];
      c = __builtin_amdgcn_mfma_f32_16x16x32_bf16(a[m][0], b[n][0], c, 0, 0, 0);
      c = __builtin_amdgcn_mfma_f32_16x16x32_bf16(a[m][1], b[n][1], c, 0, 0, 0);
      acc[MH * 4 + m][NH * 2 + n] = c;
    }
  __builtin_amdgcn_s_setprio(0);
}

template <int EPI>
__global__ __launch_bounds__(512, 2) void gemm256(
    const short* __restrict__ A, const short* __restrict__ BT,
    const float* __restrict__ bias, const float* __restrict__ resid,
    void* __restrict__ outp, int N, int K, int lda, int ldb, int num_m) {
  __shared__ int4 smem4[131072 / 16];
  char* smc = (char*)smem4;
  const int t = threadIdx.x;
  const int w = t >> 6, lane = t & 63;
  const int wr = w >> 2, wc = w & 3;

  // bijective XCD swizzle (m204)
  const int nwg = gridDim.x, orig = blockIdx.x;
  const int q8 = nwg >> 3, r8 = nwg & 7;
  const int xcd = orig & 7, loc = orig >> 3;
  const int wg = (xcd < r8 ? xcd * (q8 + 1) : r8 * (q8 + 1) + (xcd - r8) * q8) + loc;
  const int bm = wg % num_m, bn = wg / num_m;

  const int T = K >> 6;  // K-tiles of 64 (even for all our K)

  // ds_read base pointers (swizzled; ks=1 = base^64, frag offsets are pure adds)
  int LA = wr * 16384 + (lane & 15) * 128 + ((lane >> 4) << 4);
  LA ^= ((LA >> 7) & 7) << 4;
  int LB = wc * 8192 + (lane & 15) * 128 + ((lane >> 4) << 4);
  LB ^= ((LB >> 7) & 7) << 4;
  const char* pA0k0 = smc + LA;
  const char* pA0k1 = smc + (LA ^ 64);
  const char* pA1k0 = pA0k0 + 65536;
  const char* pA1k1 = pA0k1 + 65536;
  const char* pB0k0 = smc + 32768 + LB;
  const char* pB0k1 = smc + 32768 + (LB ^ 64);
  const char* pB1k0 = pB0k0 + 65536;
  const char* pB1k1 = pB0k1 + 65536;

  // stage source pointers (pre-swizzled per-thread row/col)
  const int srow = w * 8 + (lane >> 3);
  const int scol = (((lane & 7) * 16) ^ ((lane >> 3) << 4)) >> 1;
  const short* pAg = A + (long)(bm * 256 + srow) * lda + scol;
  const short* pBg = BT + (long)(bn * 256 + srow) * ldb + scol;

  f32x4 acc[8][4];
#pragma unroll
  for (int i = 0; i < 8; ++i)
#pragma unroll
    for (int j = 0; j < 4; ++j) acc[i][j] = (f32x4){0.f, 0.f, 0.f, 0.f};

  bf16x8 a0[4][2], a1[4][2], b0f[2][2], b1f[2][2];

  // ---- prologue: s1 b0.A0, s2 b0.B0, s3 b0.B1, s4 b0.A1, s5 b1.A0
  stg(smc, 0, pAg, lda, 0, 0, w);
  stg(smc, 32768, pBg, ldb, 0, 0, w);
  stg(smc, 32768, pBg, ldb, 1, 0, w);
  stg(smc, 0, pAg, lda, 1, 0, w);
  stg(smc, 65536, pAg, lda, 0, 64, w);
  VMW8();  // completes s1 (b0.A0)
  BAR();
  rdA2<0, 0>(pA0k0, pA0k1, a0);
  rdA2<0, 1>(pA0k0, pA0k1, a0);
  stg(smc, 98304, pBg, ldb, 0, 64, w);  // s6 b1.B0
  VMW6();  // completes s2,s3 (b0.B0, b0.B1)
  BAR();

  for (int t2 = 0; t2 < T; t2 += 2) {
    const int kc1 = (t2 + 1) * 64;
    const int kc2 = (t2 + 2 < T ? t2 + 2 : 0) * 64;
    const int kc3 = (t2 + 3 < T ? t2 + 3 : 0) * 64;
    // P1: rd b0.{B0,B1} | st b1.B1(t2+1) | MFMA(t2,00)
    rdB2<0>(pB0k0, pB0k1, b0f);
    rdB2<1>(pB0k0, pB0k1, b1f);
    stg(smc, 98304, pBg, ldb, 1, kc1, w);
    VMW6(); BAR();
    mq<0, 0>(a0, b0f, acc);
    // P2: rd b0.A1 | st b1.A1(t2+1) | MFMA(t2,01)
    rdA2<1, 0>(pA0k0, pA0k1, a1);
    rdA2<1, 1>(pA0k0, pA0k1, a1);
    stg(smc, 65536, pAg, lda, 1, kc1, w);
    VMW6(); BAR();
    mq<0, 1>(a0, b1f, acc);
    // P3: rd b1.A0lo (t2+1) | st b0.A0(t2+2) | MFMA(t2,11)
    rdA2<0, 0>(pA1k0, pA1k1, a0);
    stg(smc, 0, pAg, lda, 0, kc2, w);
    VMW6(); BAR();
    mq<1, 1>(a1, b1f, acc);
    // P4: rd b1.A0hi | st b0.B0(t2+2) | MFMA(t2,10)
    rdA2<0, 1>(pA1k0, pA1k1, a0);
    stg(smc, 32768, pBg, ldb, 0, kc2, w);
    VMW6(); BAR();
    mq<1, 0>(a1, b0f, acc);
    // P5: rd b1.{B0,B1} | st b0.B1(t2+2) | MFMA(t2+1,00)
    rdB2<0>(pB1k0, pB1k1, b0f);
    rdB2<1>(pB1k0, pB1k1, b1f);
    stg(smc, 32768, pBg, ldb, 1, kc2, w);
    VMW6(); BAR();
    mq<0, 0>(a0, b0f, acc);
    // P6: rd b1.A1 | st b0.A1(t2+2) | MFMA(t2+1,01)
    rdA2<1, 0>(pA1k0, pA1k1, a1);
    rdA2<1, 1>(pA1k0, pA1k1, a1);
    stg(smc, 0, pAg, lda, 1, kc2, w);
    VMW6(); BAR();
    mq<0, 1>(a0, b1f, acc);
    // P7: rd b0.A0lo (t2+2) | st b1.A0(t2+3) | MFMA(t2+1,11)
    rdA2<0, 0>(pA0k0, pA0k1, a0);
    stg(smc, 65536, pAg, lda, 0, kc3, w);
    VMW6(); BAR();
    mq<1, 1>(a1, b1f, acc);
    // P8: rd b0.A0hi | st b1.B0(t2+3) | MFMA(t2+1,10)
    rdA2<0, 1>(pA0k0, pA0k1, a0);
    stg(smc, 98304, pBg, ldb, 0, kc3, w);
    VMW6(); BAR();
    mq<1, 0>(a1, b0f, acc);
  }
  VMW0();

  // ---- epilogue ----
  const int r0 = bm * 256 + wr * 128 + ((lane >> 4) << 2);
  const int c0 = bn * 256 + wc * 64 + (lane & 15);
#pragma unroll
  for (int mi = 0; mi < 8; ++mi) {
#pragma unroll
    for (int ni = 0; ni < 4; ++ni) {
      const int col = c0 + ni * 16;
      const float bv = bias ? bias[col] : 0.f;
#pragma unroll
      for (int rr = 0; rr < 4; ++rr) {
        const int row = r0 + mi * 16 + rr;
        const long idx = (long)row * N + col;
        float v = acc[mi][ni][rr] + bv;
        if (EPI == 0) {
          ((float*)outp)[idx] = v;
        } else if (EPI == 1) {
          ((float*)outp)[idx] = v + resid[idx];
        } else if (EPI == 2) {
          ((short*)outp)[idx] = f2bf(v);
        } else {
          v = v / (1.f + __expf(-v));
          ((short*)outp)[idx] = f2bf(v);
        }
      }
    }
  }
}

// ---------------------------------------------------------------------------
// Row LayerNorm over D=1024, fp32 in -> bf16 out. One block (256 thr) per row.
// ---------------------------------------------------------------------------
__global__ __launch_bounds__(256) void ln_rows(const float* __restrict__ in,
                                               const float* __restrict__ g,
                                               const float* __restrict__ bta,
                                               short* __restrict__ outp) {
  const int row = blockIdx.x;
  const int t = threadIdx.x;
  const float4 v = ((const float4*)(in + (long)row * DD))[t];
  float s = v.x + v.y + v.z + v.w;
  float ss = v.x * v.x + v.y * v.y + v.z * v.z + v.w * v.w;
#pragma unroll
  for (int off = 1; off < 64; off <<= 1) {
    s += __shfl_xor(s, off);
    ss += __shfl_xor(ss, off);
  }
  __shared__ float red[8];
  const int w = t >> 6, lane = t & 63;
  if (lane == 0) { red[w] = s; red[4 + w] = ss; }
  __syncthreads();
  s = red[0] + red[1] + red[2] + red[3];
  ss = red[4] + red[5] + red[6] + red[7];
  const float mu = s * (1.f / DD);
  const float var = ss * (1.f / DD) - mu * mu;
  const float rs = rsqrtf(var + EPSF);
  const float4 gv = ((const float4*)g)[t];
  const float4 bv = ((const float4*)bta)[t];
  short4 o;
  o.x = f2bf((v.x - mu) * rs * gv.x + bv.x);
  o.y = f2bf((v.y - mu) * rs * gv.y + bv.y);
  o.z = f2bf((v.z - mu) * rs * gv.z + bv.z);
  o.w = f2bf((v.w - mu) * rs * gv.w + bv.w);
  ((short4*)(outp + (long)row * DD))[t] = o;
}

// ---------------------------------------------------------------------------
// Transpose + fp32->bf16 convert: W[K][N] -> WT[N][K]. 64x64 tiles.
// ---------------------------------------------------------------------------
__global__ __launch_bounds__(256) void tconv(const float* __restrict__ W,
                                             short* __restrict__ WT, int K, int N) {
  __shared__ float tile[64][65];
  const int k0 = blockIdx.x * 64, n0 = blockIdx.y * 64;
  const int t = threadIdx.x;
  const int tr = t >> 6, tc = t & 63;
#pragma unroll
  for (int i = 0; i < 64; i += 4)
    tile[i + tr][tc] = W[(long)(k0 + i + tr) * N + n0 + tc];
  __syncthreads();
#pragma unroll
  for (int i = 0; i < 64; i += 4)
    WT[(long)(n0 + i + tr) * K + k0 + tc] = f2bf(tile[tc][i + tr]);
}

// ---------------------------------------------------------------------------
// ctx[b,h,d,e] = sum_m softmax_d(k[b,m,h,:])[d] * v[b,m,h,e].
// ---------------------------------------------------------------------------
__global__ __launch_bounds__(256) void ctx_kernel(const short* __restrict__ kv,
                                                  float* __restrict__ ctx) {
  const int bh = blockIdx.x;
  const int b = bh >> 4, h = bh & 15;
  const int t = threadIdx.x, g = t >> 6, lane = t & 63;
  __shared__ float ksm[4][64];
  __shared__ float vsm[4][64];
  float acc[16];
#pragma unroll
  for (int j = 0; j < 16; ++j) acc[j] = 0.f;
  const int d = t & 63;
  const int e0 = (t >> 6) * 16;
  const short* base = kv + (long)b * MTOK * 2048 + h * 64;
  for (int m0 = 0; m0 < MTOK; m0 += 4) {
    const long moff = (long)(m0 + g) * 2048;
    float kval = bf2f(base[moff + lane]);
    float vval = bf2f(base[moff + 1024 + lane]);
    float mx = kval;
#pragma unroll
    for (int off = 1; off < 64; off <<= 1) mx = fmaxf(mx, __shfl_xor(mx, off));
    float e = __expf(kval - mx);
    float sm = e;
#pragma unroll
    for (int off = 1; off < 64; off <<= 1) sm += __shfl_xor(sm, off);
    ksm[g][lane] = e / sm;
    vsm[g][lane] = vval;
    __syncthreads();
#pragma unroll
    for (int mm = 0; mm < 4; ++mm) {
      const float kd = ksm[mm][d];
#pragma unroll
      for (int j = 0; j < 16; ++j) acc[j] = fmaf(kd, vsm[mm][e0 + j], acc[j]);
    }
    __syncthreads();
  }
  float* cp = ctx + ((long)bh * 64 + d) * 64 + e0;
#pragma unroll
  for (int j = 0; j < 16; ++j) cp[j] = acc[j];
}

// ---------------------------------------------------------------------------
// Column softmax stats for q (softmax over the N axis per (b, column)).
// ---------------------------------------------------------------------------
__global__ __launch_bounds__(256) void qstat_part(const float* __restrict__ q,
                                                  float* __restrict__ pmax,
                                                  float* __restrict__ psum) {
  const int c = blockIdx.x * 256 + threadIdx.x;
  const int b = blockIdx.z, ch = blockIdx.y;
  const float* qp = q + ((long)b * NN + ch * 128) * DD + c;
  float mx = -1e30f, sm = 0.f;
  for (int r = 0; r < 128; ++r) {
    const float xv = qp[(long)r * DD];
    const float nm = fmaxf(mx, xv);
    sm = sm * __expf(mx - nm) + __expf(xv - nm);
    mx = nm;
  }
  const long idx = ((long)b * DD + c) * 32 + ch;
  pmax[idx] = mx;
  psum[idx] = sm;
}

__global__ __launch_bounds__(256) void qstat_comb(const float* __restrict__ pmax,
                                                  const float* __restrict__ psum,
                                                  float* __restrict__ cmax,
                                                  float* __restrict__ crs) {
  const int i = blockIdx.x * 256 + threadIdx.x;  // b*1024 + c
  const float* pm = pmax + (long)i * 32;
  const float* ps = psum + (long)i * 32;
  float mx = -1e30f;
#pragma unroll
  for (int ch = 0; ch < 32; ++ch) mx = fmaxf(mx, pm[ch]);
  float sm = 0.f;
#pragma unroll
  for (int ch = 0; ch < 32; ++ch) sm += ps[ch] * __expf(pm[ch] - mx);
  cmax[i] = mx;
  crs[i] = SCALE_F / sm;
}

// ---------------------------------------------------------------------------
// Fused: q_soft = exp(q-cmax)*crs (includes SCALE), out = q_soft @ ctx[b,h].
// ---------------------------------------------------------------------------
__global__ __launch_bounds__(256) void attn_apply(const float* __restrict__ q,
                                                  const float* __restrict__ ctx,
                                                  const float* __restrict__ cmax,
                                                  const float* __restrict__ crs,
                                                  short* __restrict__ outa) {
  const int b = blockIdx.z, h = blockIdx.y, n0 = blockIdx.x * 128;
  const int t = threadIdx.x, g = t >> 6, lane = t & 63;
  __shared__ float ctx_l[4096];
  __shared__ float cm[64], cs[64];
  __shared__ float qsm[4][64];
  const float* cp = ctx + (long)(b * HH + h) * 4096;
  for (int i = t; i < 4096; i += 256) ctx_l[i] = cp[i];
  if (t < 64) {
    cm[t] = cmax[(long)b * DD + h * 64 + t];
    cs[t] = crs[(long)b * DD + h * 64 + t];
  }
  __syncthreads();
  for (int i = 0; i < 32; ++i) {
    const int n = n0 + i * 4 + g;
    const long off = ((long)b * NN + n) * DD + h * 64;
    const float qv = q[off + lane];
    const float qs = __expf(qv - cm[lane]) * cs[lane];
    qsm[g][lane] = qs;  // same-wave LDS, no barrier needed
    float o = 0.f;
#pragma unroll
    for (int dd = 0; dd < 64; ++dd) o = fmaf(qsm[g][dd], ctx_l[dd * 64 + lane], o);
    outa[off + lane] = f2bf(o);
  }
}

// ---------------------------------------------------------------------------
extern "C" void kernel_launch(void* const* d_in, const int* in_sizes, int n_in,
                              void* d_out, int out_size, void* d_ws, size_t ws_size,
                              hipStream_t stream) {
  (void)in_sizes; (void)n_in; (void)out_size;
  const float* x      = (const float*)d_in[0];
  const float* wav    = (const float*)d_in[1];
  const float* ln_q_g = (const float*)d_in[2];
  const float* ln_q_b = (const float*)d_in[3];
  const float* Wq     = (const float*)d_in[4];
  const float* bq     = (const float*)d_in[5];
  const float* ln_kv_g= (const float*)d_in[6];
  const float* ln_kv_b= (const float*)d_in[7];
  const float* Wkv    = (const float*)d_in[8];
  const float* bkv    = (const float*)d_in[9];
  const float* Wo     = (const float*)d_in[10];
  const float* bo     = (const float*)d_in[11];
  const float* ln_f_g = (const float*)d_in[12];
  const float* ln_f_b = (const float*)d_in[13];
  const float* W1     = (const float*)d_in[14];
  const float* b1     = (const float*)d_in[15];
  const float* W2     = (const float*)d_in[16];
  const float* b2     = (const float*)d_in[17];
  float* outp = (float*)d_out;
  char* ws = (char*)d_ws;

  const long MR = (long)BB * NN;    // 32768 rows
  const long MKV = (long)BB * MTOK; // 8192 rows

  size_t off = 0;
  auto bump = [&](size_t bytes) {
    size_t o = off;
    off += (bytes + 255) & ~(size_t)255;
    return o;
  };
  short* WqT  = (short*)(ws + bump((size_t)DD * DD * 2));
  short* WkvT = (short*)(ws + bump((size_t)2048 * DD * 2));
  short* WoT  = (short*)(ws + bump((size_t)DD * DD * 2));
  short* W1T  = (short*)(ws + bump((size_t)4096 * DD * 2));
  short* W2T  = (short*)(ws + bump((size_t)DD * 4096 * 2));
  float* qbuf = (float*)(ws + bump((size_t)MR * DD * 4));   // later: x2 (fp32)
  short* lnbuf= (short*)(ws + bump((size_t)MR * DD * 2));   // xq_ln, later x2_ln
  float* ctx  = (float*)(ws + bump((size_t)BB * HH * 64 * 64 * 4));
  float* pmax = (float*)(ws + bump((size_t)BB * DD * 32 * 4));
  float* psum = (float*)(ws + bump((size_t)BB * DD * 32 * 4));
  float* cmax = (float*)(ws + bump((size_t)BB * DD * 4));
  float* crs  = (float*)(ws + bump((size_t)BB * DD * 4));
  const size_t dyn0 = off;
  short* wvln  = (short*)(ws + dyn0);
  short* kvbuf = (short*)(ws + dyn0 + (size_t)MKV * DD * 2);
  short* oattn = (short*)(ws + dyn0);  // reuses wvln+kv region (dead by then)
  short* hbuf  = (short*)(ws + dyn0);  // MLP phase (oattn dead by then)

  size_t avail = ws_size > dyn0 ? ws_size - dyn0 : 0;
  int CS = 4096;
  while (CS > 256 && (size_t)MR * CS * 2 > avail) CS >>= 1;

  const int nm = (int)(MR / 256);    // 128
  const int nmkv = (int)(MKV / 256); // 32

  // 1) weight convert+transpose to bf16 [N][K]
  tconv<<<dim3(DD / 64, DD / 64), 256, 0, stream>>>(Wq, WqT, DD, DD);
  tconv<<<dim3(DD / 64, 2048 / 64), 256, 0, stream>>>(Wkv, WkvT, DD, 2048);
  tconv<<<dim3(DD / 64, DD / 64), 256, 0, stream>>>(Wo, WoT, DD, DD);
  tconv<<<dim3(DD / 64, 4096 / 64), 256, 0, stream>>>(W1, W1T, DD, 4096);
  tconv<<<dim3(4096 / 64, DD / 64), 256, 0, stream>>>(W2, W2T, 4096, DD);

  // 2) LayerNorms -> bf16
  ln_rows<<<dim3((unsigned)MR), 256, 0, stream>>>(x, ln_q_g, ln_q_b, lnbuf);
  ln_rows<<<dim3((unsigned)MKV), 256, 0, stream>>>(wav, ln_kv_g, ln_kv_b, wvln);

  // 3) q = LN(x) @ Wq + bq   (fp32 out, needed for column softmax)
  gemm256<0><<<dim3((unsigned)(nm * (DD / 256))), 512, 0, stream>>>(
      lnbuf, WqT, bq, nullptr, qbuf, DD, DD, DD, DD, nm);
  // 4) kv = LN(wav) @ Wkv + bkv  (bf16 out)
  gemm256<2><<<dim3((unsigned)(nmkv * (2048 / 256))), 512, 0, stream>>>(
      wvln, WkvT, bkv, nullptr, kvbuf, 2048, DD, DD, DD, nmkv);
  // 5) context per (b,h)
  ctx_kernel<<<dim3(BB * HH), 256, 0, stream>>>(kvbuf, ctx);
  // 6) q column-softmax stats
  qstat_part<<<dim3(DD / 256, 32, BB), 256, 0, stream>>>(qbuf, pmax, psum);
  qstat_comb<<<dim3(BB * DD / 256), 256, 0, stream>>>(pmax, psum, cmax, crs);
  // 7) softmax-apply + per-head 64x64 matmul -> out_attn (bf16, overwrites kv)
  attn_apply<<<dim3(NN / 128, HH, BB), 256, 0, stream>>>(qbuf, ctx, cmax, crs, oattn);
  // 8) x2 = out_attn @ Wo + bo + x   (fp32, overwrites q)
  gemm256<1><<<dim3((unsigned)(nm * (DD / 256))), 512, 0, stream>>>(
      oattn, WoT, bo, x, qbuf, DD, DD, DD, DD, nm);
  float* x2 = qbuf;
  // 9) LN_f(x2) -> bf16
  ln_rows<<<dim3((unsigned)MR), 256, 0, stream>>>(x2, ln_f_g, ln_f_b, lnbuf);
  // 10) MLP: h = silu(x2ln @ W1 + b1); out = x2 + h @ W2 + b2
  for (int c0 = 0; c0 < 4096; c0 += CS) {
    gemm256<3><<<dim3((unsigned)(nm * (CS / 256))), 512, 0, stream>>>(
        lnbuf, W1T + (long)c0 * DD, b1 + c0, nullptr, hbuf, CS, DD, DD, DD, nm);
    gemm256<1><<<dim3((unsigned)(nm * (DD / 256))), 512, 0, stream>>>(
        hbuf, W2T + c0, (c0 == 0) ? b2 : nullptr,
        (c0 == 0) ? (const float*)x2 : (const float*)outp, outp, DD, CS, CS, 4096, nm);
  }
}

// Round 6
// 1307.955 us; speedup vs baseline: 1.3535x; 1.0301x over previous
//
#include <hip/hip_runtime.h>
#include <stdint.h>
#include <stddef.h>

#define BB 8
#define NN 4096
#define MTOK 1024
#define DD 1024
#define HH 16
#define EPSF 1e-6f
static const float SCALE_F = 0.125f; // HD^-0.5, HD=64

typedef __attribute__((ext_vector_type(4))) float f32x4;
typedef __attribute__((ext_vector_type(8))) short bf16x8;

__device__ __forceinline__ short f2bf(float f) {
  union { float f; uint32_t u; } x; x.f = f;
  uint32_t r = (x.u + 0x7fffu + ((x.u >> 16) & 1u)) >> 16;
  return (short)(uint16_t)r;
}
__device__ __forceinline__ float bf2f(short s) {
  union { uint32_t u; float f; } x; x.u = ((uint32_t)(uint16_t)s) << 16;
  return x.f;
}

#if defined(__HIP_DEVICE_COMPILE__) && __has_builtin(__builtin_amdgcn_global_load_lds)
#define USE_GLOAD_LDS 1
#else
#define USE_GLOAD_LDS 0
#endif

#define BAR() __builtin_amdgcn_s_barrier()
#if USE_GLOAD_LDS
#define VMW6() asm volatile("s_waitcnt vmcnt(6)" ::: "memory")
#define VMW8() asm volatile("s_waitcnt vmcnt(8)" ::: "memory")
#else
// fallback staging uses plain LDS stores -> must drain lgkm before barriers
#define VMW6() asm volatile("s_waitcnt vmcnt(0) lgkmcnt(0)" ::: "memory")
#define VMW8() asm volatile("s_waitcnt vmcnt(0) lgkmcnt(0)" ::: "memory")
#endif
#define VMW0() asm volatile("s_waitcnt vmcnt(0)" ::: "memory")

// ---------------------------------------------------------------------------
// 256x256 8-phase bf16 GEMM, read-ahead pipelined (T1+T2+T3+T4+T5).
// C = A[M,K] @ BT[N,K]^T + bias. 512 thr = 8 waves (2M x 4N), BK=64,
// LDS 128 KiB (2 bufs x {A 32K, B 32K}). Swizzle: byte ^= ((byte>>7)&7)<<4,
// pre-applied on global stage source (linear global_load_lds dest) and on
// precomputed ds_read base pointers.
// Tile mapping is ROW-MAJOR over (bm,bn) so each XCD's contiguous swizzled
// chunk = consecutive bm-rows: A-panel stays L2-hot across the 16-bn run and
// B becomes L3-resident (cuts the 8x A over-fetch seen at column-major).
// EPI: 0 f32 acc+bias | 1 f32 acc+bias+resid | 2 bf16 acc+bias | 3 bf16 silu
// ---------------------------------------------------------------------------
__device__ __forceinline__ bf16x8 ldsld(const char* p, int off) {
  return *(const bf16x8*)(p + off);
}
template <int MH, int MLO>
__device__ __forceinline__ void rdA2(const char* k0, const char* k1, bf16x8 a[4][2]) {
#pragma unroll
  for (int m = MLO * 2; m < MLO * 2 + 2; ++m) {
    a[m][0] = ldsld(k0, MH * 8192 + m * 2048);
    a[m][1] = ldsld(k1, MH * 8192 + m * 2048);
  }
}
template <int NH>
__device__ __forceinline__ void rdB2(const char* k0, const char* k1, bf16x8 b[2][2]) {
#pragma unroll
  for (int n = 0; n < 2; ++n) {
    b[n][0] = ldsld(k0, NH * 4096 + n * 2048);
    b[n][1] = ldsld(k1, NH * 4096 + n * 2048);
  }
}
// Stage one 16KB half-tile (rows smh*64..+64 and 128+smh*64..+64 of a 256x64
// operand tile). pg already encodes the per-thread swizzled (row,col).
__device__ __forceinline__ void stg(char* smc, int ldsbase, const short* pg,
                                    int ld, int smh, int k, int w) {
#pragma unroll
  for (int i = 0; i < 2; ++i) {
    const short* src = pg + (long)(smh * 64 + i * 128) * ld + k;
#if USE_GLOAD_LDS
    __builtin_amdgcn_global_load_lds(
        (const __attribute__((address_space(1))) void*)src,
        (__attribute__((address_space(3))) void*)(smc + ldsbase + i * 16384 +
                                                  smh * 8192 + w * 1024),
        16, 0, 0);
#else
    *(bf16x8*)(smc + ldsbase + i * 16384 + smh * 8192 + w * 1024 +
               (int)(threadIdx.x & 63) * 16) = *(const bf16x8*)src;
#endif
  }
}
template <int MH, int NH>
__device__ __forceinline__ void mq(const bf16x8 a[4][2], const bf16x8 b[2][2],
                                   f32x4 acc[8][4]) {
  __builtin_amdgcn_s_setprio(1);
#pragma unroll
  for (int m = 0; m < 4; ++m)
#pragma unroll
    for (int n = 0; n < 2; ++n) {
      f32x4 c = acc[MH * 4 + m][NH * 2 + n];
      c = __builtin_amdgcn_mfma_f32_16x16x32_bf16(a[m][0], b[n][0], c, 0, 0, 0);
      c = __builtin_amdgcn_mfma_f32_16x16x32_bf16(a[m][1], b[n][1], c, 0, 0, 0);
      acc[MH * 4 + m][NH * 2 + n] = c;
    }
  __builtin_amdgcn_s_setprio(0);
}

template <int EPI>
__global__ __launch_bounds__(512, 2) void gemm256(
    const short* __restrict__ A, const short* __restrict__ BT,
    const float* __restrict__ bias, const float* __restrict__ resid,
    void* __restrict__ outp, int N, int K, int lda, int ldb, int num_n) {
  __shared__ int4 smem4[131072 / 16];
  char* smc = (char*)smem4;
  const int t = threadIdx.x;
  const int w = t >> 6, lane = t & 63;
  const int wr = w >> 2, wc = w & 3;

  // bijective XCD swizzle (m204)
  const int nwg = gridDim.x, orig = blockIdx.x;
  const int q8 = nwg >> 3, r8 = nwg & 7;
  const int xcd = orig & 7, loc = orig >> 3;
  const int wg = (xcd < r8 ? xcd * (q8 + 1) : r8 * (q8 + 1) + (xcd - r8) * q8) + loc;
  // ROW-major tile mapping: consecutive wg (same XCD) share the A panel.
  const int bm = wg / num_n, bn = wg % num_n;

  const int T = K >> 6;  // K-tiles of 64 (even for all our K)

  // ds_read base pointers (swizzled; ks=1 = base^64, frag offsets are pure adds)
  int LA = wr * 16384 + (lane & 15) * 128 + ((lane >> 4) << 4);
  LA ^= ((LA >> 7) & 7) << 4;
  int LB = wc * 8192 + (lane & 15) * 128 + ((lane >> 4) << 4);
  LB ^= ((LB >> 7) & 7) << 4;
  const char* pA0k0 = smc + LA;
  const char* pA0k1 = smc + (LA ^ 64);
  const char* pA1k0 = pA0k0 + 65536;
  const char* pA1k1 = pA0k1 + 65536;
  const char* pB0k0 = smc + 32768 + LB;
  const char* pB0k1 = smc + 32768 + (LB ^ 64);
  const char* pB1k0 = pB0k0 + 65536;
  const char* pB1k1 = pB0k1 + 65536;

  // stage source pointers (pre-swizzled per-thread row/col)
  const int srow = w * 8 + (lane >> 3);
  const int scol = (((lane & 7) * 16) ^ ((lane >> 3) << 4)) >> 1;
  const short* pAg = A + (long)(bm * 256 + srow) * lda + scol;
  const short* pBg = BT + (long)(bn * 256 + srow) * ldb + scol;

  f32x4 acc[8][4];
#pragma unroll
  for (int i = 0; i < 8; ++i)
#pragma unroll
    for (int j = 0; j < 4; ++j) acc[i][j] = (f32x4){0.f, 0.f, 0.f, 0.f};

  bf16x8 a0[4][2], a1[4][2], b0f[2][2], b1f[2][2];

  // ---- prologue: s1 b0.A0, s2 b0.B0, s3 b0.B1, s4 b0.A1, s5 b1.A0
  stg(smc, 0, pAg, lda, 0, 0, w);
  stg(smc, 32768, pBg, ldb, 0, 0, w);
  stg(smc, 32768, pBg, ldb, 1, 0, w);
  stg(smc, 0, pAg, lda, 1, 0, w);
  stg(smc, 65536, pAg, lda, 0, 64, w);
  VMW8();  // completes s1 (b0.A0)
  BAR();
  rdA2<0, 0>(pA0k0, pA0k1, a0);
  rdA2<0, 1>(pA0k0, pA0k1, a0);
  stg(smc, 98304, pBg, ldb, 0, 64, w);  // s6 b1.B0
  VMW6();  // completes s2,s3 (b0.B0, b0.B1)
  BAR();

  for (int t2 = 0; t2 < T; t2 += 2) {
    const int kc1 = (t2 + 1) * 64;
    const int kc2 = (t2 + 2 < T ? t2 + 2 : 0) * 64;
    const int kc3 = (t2 + 3 < T ? t2 + 3 : 0) * 64;
    // P1: rd b0.{B0,B1} | st b1.B1(t2+1) | MFMA(t2,00)
    rdB2<0>(pB0k0, pB0k1, b0f);
    rdB2<1>(pB0k0, pB0k1, b1f);
    stg(smc, 98304, pBg, ldb, 1, kc1, w);
    VMW6(); BAR();
    mq<0, 0>(a0, b0f, acc);
    // P2: rd b0.A1 | st b1.A1(t2+1) | MFMA(t2,01)
    rdA2<1, 0>(pA0k0, pA0k1, a1);
    rdA2<1, 1>(pA0k0, pA0k1, a1);
    stg(smc, 65536, pAg, lda, 1, kc1, w);
    VMW6(); BAR();
    mq<0, 1>(a0, b1f, acc);
    // P3: rd b1.A0lo (t2+1) | st b0.A0(t2+2) | MFMA(t2,11)
    rdA2<0, 0>(pA1k0, pA1k1, a0);
    stg(smc, 0, pAg, lda, 0, kc2, w);
    VMW6(); BAR();
    mq<1, 1>(a1, b1f, acc);
    // P4: rd b1.A0hi | st b0.B0(t2+2) | MFMA(t2,10)
    rdA2<0, 1>(pA1k0, pA1k1, a0);
    stg(smc, 32768, pBg, ldb, 0, kc2, w);
    VMW6(); BAR();
    mq<1, 0>(a1, b0f, acc);
    // P5: rd b1.{B0,B1} | st b0.B1(t2+2) | MFMA(t2+1,00)
    rdB2<0>(pB1k0, pB1k1, b0f);
    rdB2<1>(pB1k0, pB1k1, b1f);
    stg(smc, 32768, pBg, ldb, 1, kc2, w);
    VMW6(); BAR();
    mq<0, 0>(a0, b0f, acc);
    // P6: rd b1.A1 | st b0.A1(t2+2) | MFMA(t2+1,01)
    rdA2<1, 0>(pA1k0, pA1k1, a1);
    rdA2<1, 1>(pA1k0, pA1k1, a1);
    stg(smc, 0, pAg, lda, 1, kc2, w);
    VMW6(); BAR();
    mq<0, 1>(a0, b1f, acc);
    // P7: rd b0.A0lo (t2+2) | st b1.A0(t2+3) | MFMA(t2+1,11)
    rdA2<0, 0>(pA0k0, pA0k1, a0);
    stg(smc, 65536, pAg, lda, 0, kc3, w);
    VMW6(); BAR();
    mq<1, 1>(a1, b1f, acc);
    // P8: rd b0.A0hi | st b1.B0(t2+3) | MFMA(t2+1,10)
    rdA2<0, 1>(pA0k0, pA0k1, a0);
    stg(smc, 98304, pBg, ldb, 0, kc3, w);
    VMW6(); BAR();
    mq<1, 0>(a1, b0f, acc);
  }
  VMW0();

  // ---- epilogue ----
  const int r0 = bm * 256 + wr * 128 + ((lane >> 4) << 2);
  const int c0 = bn * 256 + wc * 64 + (lane & 15);
#pragma unroll
  for (int mi = 0; mi < 8; ++mi) {
#pragma unroll
    for (int ni = 0; ni < 4; ++ni) {
      const int col = c0 + ni * 16;
      const float bv = bias ? bias[col] : 0.f;
#pragma unroll
      for (int rr = 0; rr < 4; ++rr) {
        const int row = r0 + mi * 16 + rr;
        const long idx = (long)row * N + col;
        float v = acc[mi][ni][rr] + bv;
        if (EPI == 0) {
          ((float*)outp)[idx] = v;
        } else if (EPI == 1) {
          ((float*)outp)[idx] = v + resid[idx];
        } else if (EPI == 2) {
          ((short*)outp)[idx] = f2bf(v);
        } else {
          v = v / (1.f + __expf(-v));
          ((short*)outp)[idx] = f2bf(v);
        }
      }
    }
  }
}

// ---------------------------------------------------------------------------
// Row LayerNorm over D=1024, fp32 in -> bf16 out. One block (256 thr) per row.
// ---------------------------------------------------------------------------
__global__ __launch_bounds__(256) void ln_rows(const float* __restrict__ in,
                                               const float* __restrict__ g,
                                               const float* __restrict__ bta,
                                               short* __restrict__ outp) {
  const int row = blockIdx.x;
  const int t = threadIdx.x;
  const float4 v = ((const float4*)(in + (long)row * DD))[t];
  float s = v.x + v.y + v.z + v.w;
  float ss = v.x * v.x + v.y * v.y + v.z * v.z + v.w * v.w;
#pragma unroll
  for (int off = 1; off < 64; off <<= 1) {
    s += __shfl_xor(s, off);
    ss += __shfl_xor(ss, off);
  }
  __shared__ float red[8];
  const int w = t >> 6, lane = t & 63;
  if (lane == 0) { red[w] = s; red[4 + w] = ss; }
  __syncthreads();
  s = red[0] + red[1] + red[2] + red[3];
  ss = red[4] + red[5] + red[6] + red[7];
  const float mu = s * (1.f / DD);
  const float var = ss * (1.f / DD) - mu * mu;
  const float rs = rsqrtf(var + EPSF);
  const float4 gv = ((const float4*)g)[t];
  const float4 bv = ((const float4*)bta)[t];
  short4 o;
  o.x = f2bf((v.x - mu) * rs * gv.x + bv.x);
  o.y = f2bf((v.y - mu) * rs * gv.y + bv.y);
  o.z = f2bf((v.z - mu) * rs * gv.z + bv.z);
  o.w = f2bf((v.w - mu) * rs * gv.w + bv.w);
  ((short4*)(outp + (long)row * DD))[t] = o;
}

// ---------------------------------------------------------------------------
// Transpose + fp32->bf16 convert: W[K][N] -> WT[N][K]. 64x64 tiles.
// ---------------------------------------------------------------------------
__global__ __launch_bounds__(256) void tconv(const float* __restrict__ W,
                                             short* __restrict__ WT, int K, int N) {
  __shared__ float tile[64][65];
  const int k0 = blockIdx.x * 64, n0 = blockIdx.y * 64;
  const int t = threadIdx.x;
  const int tr = t >> 6, tc = t & 63;
#pragma unroll
  for (int i = 0; i < 64; i += 4)
    tile[i + tr][tc] = W[(long)(k0 + i + tr) * N + n0 + tc];
  __syncthreads();
#pragma unroll
  for (int i = 0; i < 64; i += 4)
    WT[(long)(n0 + i + tr) * K + k0 + tc] = f2bf(tile[tc][i + tr]);
}

// ---------------------------------------------------------------------------
// ctx[b,h,d,e] = sum_m softmax_d(k[b,m,h,:])[d] * v[b,m,h,e].
// ---------------------------------------------------------------------------
__global__ __launch_bounds__(256) void ctx_kernel(const short* __restrict__ kv,
                                                  float* __restrict__ ctx) {
  const int bh = blockIdx.x;
  const int b = bh >> 4, h = bh & 15;
  const int t = threadIdx.x, g = t >> 6, lane = t & 63;
  __shared__ float ksm[4][64];
  __shared__ float vsm[4][64];
  float acc[16];
#pragma unroll
  for (int j = 0; j < 16; ++j) acc[j] = 0.f;
  const int d = t & 63;
  const int e0 = (t >> 6) * 16;
  const short* base = kv + (long)b * MTOK * 2048 + h * 64;
  for (int m0 = 0; m0 < MTOK; m0 += 4) {
    const long moff = (long)(m0 + g) * 2048;
    float kval = bf2f(base[moff + lane]);
    float vval = bf2f(base[moff + 1024 + lane]);
    float mx = kval;
#pragma unroll
    for (int off = 1; off < 64; off <<= 1) mx = fmaxf(mx, __shfl_xor(mx, off));
    float e = __expf(kval - mx);
    float sm = e;
#pragma unroll
    for (int off = 1; off < 64; off <<= 1) sm += __shfl_xor(sm, off);
    ksm[g][lane] = e / sm;
    vsm[g][lane] = vval;
    __syncthreads();
#pragma unroll
    for (int mm = 0; mm < 4; ++mm) {
      const float kd = ksm[mm][d];
#pragma unroll
      for (int j = 0; j < 16; ++j) acc[j] = fmaf(kd, vsm[mm][e0 + j], acc[j]);
    }
    __syncthreads();
  }
  float* cp = ctx + ((long)bh * 64 + d) * 64 + e0;
#pragma unroll
  for (int j = 0; j < 16; ++j) cp[j] = acc[j];
}

// ---------------------------------------------------------------------------
// Column softmax stats for q (softmax over the N axis per (b, column)).
// ---------------------------------------------------------------------------
__global__ __launch_bounds__(256) void qstat_part(const float* __restrict__ q,
                                                  float* __restrict__ pmax,
                                                  float* __restrict__ psum) {
  const int c = blockIdx.x * 256 + threadIdx.x;
  const int b = blockIdx.z, ch = blockIdx.y;
  const float* qp = q + ((long)b * NN + ch * 128) * DD + c;
  float mx = -1e30f, sm = 0.f;
  for (int r = 0; r < 128; ++r) {
    const float xv = qp[(long)r * DD];
    const float nm = fmaxf(mx, xv);
    sm = sm * __expf(mx - nm) + __expf(xv - nm);
    mx = nm;
  }
  const long idx = ((long)b * DD + c) * 32 + ch;
  pmax[idx] = mx;
  psum[idx] = sm;
}

__global__ __launch_bounds__(256) void qstat_comb(const float* __restrict__ pmax,
                                                  const float* __restrict__ psum,
                                                  float* __restrict__ cmax,
                                                  float* __restrict__ crs) {
  const int i = blockIdx.x * 256 + threadIdx.x;  // b*1024 + c
  const float* pm = pmax + (long)i * 32;
  const float* ps = psum + (long)i * 32;
  float mx = -1e30f;
#pragma unroll
  for (int ch = 0; ch < 32; ++ch) mx = fmaxf(mx, pm[ch]);
  float sm = 0.f;
#pragma unroll
  for (int ch = 0; ch < 32; ++ch) sm += ps[ch] * __expf(pm[ch] - mx);
  cmax[i] = mx;
  crs[i] = SCALE_F / sm;
}

// ---------------------------------------------------------------------------
// Fused: q_soft = exp(q-cmax)*crs (includes SCALE), out = q_soft @ ctx[b,h].
// ---------------------------------------------------------------------------
__global__ __launch_bounds__(256) void attn_apply(const float* __restrict__ q,
                                                  const float* __restrict__ ctx,
                                                  const float* __restrict__ cmax,
                                                  const float* __restrict__ crs,
                                                  short* __restrict__ outa) {
  const int b = blockIdx.z, h = blockIdx.y, n0 = blockIdx.x * 128;
  const int t = threadIdx.x, g = t >> 6, lane = t & 63;
  __shared__ float ctx_l[4096];
  __shared__ float cm[64], cs[64];
  __shared__ float qsm[4][64];
  const float* cp = ctx + (long)(b * HH + h) * 4096;
  for (int i = t; i < 4096; i += 256) ctx_l[i] = cp[i];
  if (t < 64) {
    cm[t] = cmax[(long)b * DD + h * 64 + t];
    cs[t] = crs[(long)b * DD + h * 64 + t];
  }
  __syncthreads();
  for (int i = 0; i < 32; ++i) {
    const int n = n0 + i * 4 + g;
    const long off = ((long)b * NN + n) * DD + h * 64;
    const float qv = q[off + lane];
    const float qs = __expf(qv - cm[lane]) * cs[lane];
    qsm[g][lane] = qs;  // same-wave LDS, no barrier needed
    float o = 0.f;
#pragma unroll
    for (int dd = 0; dd < 64; ++dd) o = fmaf(qsm[g][dd], ctx_l[dd * 64 + lane], o);
    outa[off + lane] = f2bf(o);
  }
}

// ---------------------------------------------------------------------------
extern "C" void kernel_launch(void* const* d_in, const int* in_sizes, int n_in,
                              void* d_out, int out_size, void* d_ws, size_t ws_size,
                              hipStream_t stream) {
  (void)in_sizes; (void)n_in; (void)out_size;
  const float* x      = (const float*)d_in[0];
  const float* wav    = (const float*)d_in[1];
  const float* ln_q_g = (const float*)d_in[2];
  const float* ln_q_b = (const float*)d_in[3];
  const float* Wq     = (const float*)d_in[4];
  const float* bq     = (const float*)d_in[5];
  const float* ln_kv_g= (const float*)d_in[6];
  const float* ln_kv_b= (const float*)d_in[7];
  const float* Wkv    = (const float*)d_in[8];
  const float* bkv    = (const float*)d_in[9];
  const float* Wo     = (const float*)d_in[10];
  const float* bo     = (const float*)d_in[11];
  const float* ln_f_g = (const float*)d_in[12];
  const float* ln_f_b = (const float*)d_in[13];
  const float* W1     = (const float*)d_in[14];
  const float* b1     = (const float*)d_in[15];
  const float* W2     = (const float*)d_in[16];
  const float* b2     = (const float*)d_in[17];
  float* outp = (float*)d_out;
  char* ws = (char*)d_ws;

  const long MR = (long)BB * NN;    // 32768 rows
  const long MKV = (long)BB * MTOK; // 8192 rows

  size_t off = 0;
  auto bump = [&](size_t bytes) {
    size_t o = off;
    off += (bytes + 255) & ~(size_t)255;
    return o;
  };
  short* WqT  = (short*)(ws + bump((size_t)DD * DD * 2));
  short* WkvT = (short*)(ws + bump((size_t)2048 * DD * 2));
  short* WoT  = (short*)(ws + bump((size_t)DD * DD * 2));
  short* W1T  = (short*)(ws + bump((size_t)4096 * DD * 2));
  short* W2T  = (short*)(ws + bump((size_t)DD * 4096 * 2));
  float* qbuf = (float*)(ws + bump((size_t)MR * DD * 4));   // later: x2 (fp32)
  short* lnbuf= (short*)(ws + bump((size_t)MR * DD * 2));   // xq_ln, later x2_ln
  float* ctx  = (float*)(ws + bump((size_t)BB * HH * 64 * 64 * 4));
  float* pmax = (float*)(ws + bump((size_t)BB * DD * 32 * 4));
  float* psum = (float*)(ws + bump((size_t)BB * DD * 32 * 4));
  float* cmax = (float*)(ws + bump((size_t)BB * DD * 4));
  float* crs  = (float*)(ws + bump((size_t)BB * DD * 4));
  const size_t dyn0 = off;
  short* wvln  = (short*)(ws + dyn0);
  short* kvbuf = (short*)(ws + dyn0 + (size_t)MKV * DD * 2);
  short* oattn = (short*)(ws + dyn0);  // reuses wvln+kv region (dead by then)
  short* hbuf  = (short*)(ws + dyn0);  // MLP phase (oattn dead by then)

  size_t avail = ws_size > dyn0 ? ws_size - dyn0 : 0;
  int CS = 4096;
  while (CS > 256 && (size_t)MR * CS * 2 > avail) CS >>= 1;

  const int nm = (int)(MR / 256);    // 128
  const int nmkv = (int)(MKV / 256); // 32

  // 1) weight convert+transpose to bf16 [N][K]
  tconv<<<dim3(DD / 64, DD / 64), 256, 0, stream>>>(Wq, WqT, DD, DD);
  tconv<<<dim3(DD / 64, 2048 / 64), 256, 0, stream>>>(Wkv, WkvT, DD, 2048);
  tconv<<<dim3(DD / 64, DD / 64), 256, 0, stream>>>(Wo, WoT, DD, DD);
  tconv<<<dim3(DD / 64, 4096 / 64), 256, 0, stream>>>(W1, W1T, DD, 4096);
  tconv<<<dim3(4096 / 64, DD / 64), 256, 0, stream>>>(W2, W2T, 4096, DD);

  // 2) LayerNorms -> bf16
  ln_rows<<<dim3((unsigned)MR), 256, 0, stream>>>(x, ln_q_g, ln_q_b, lnbuf);
  ln_rows<<<dim3((unsigned)MKV), 256, 0, stream>>>(wav, ln_kv_g, ln_kv_b, wvln);

  // 3) q = LN(x) @ Wq + bq   (fp32 out, needed for column softmax)
  gemm256<0><<<dim3((unsigned)(nm * (DD / 256))), 512, 0, stream>>>(
      lnbuf, WqT, bq, nullptr, qbuf, DD, DD, DD, DD, DD / 256);
  // 4) kv = LN(wav) @ Wkv + bkv  (bf16 out)
  gemm256<2><<<dim3((unsigned)(nmkv * (2048 / 256))), 512, 0, stream>>>(
      wvln, WkvT, bkv, nullptr, kvbuf, 2048, DD, DD, DD, 2048 / 256);
  // 5) context per (b,h)
  ctx_kernel<<<dim3(BB * HH), 256, 0, stream>>>(kvbuf, ctx);
  // 6) q column-softmax stats
  qstat_part<<<dim3(DD / 256, 32, BB), 256, 0, stream>>>(qbuf, pmax, psum);
  qstat_comb<<<dim3(BB * DD / 256), 256, 0, stream>>>(pmax, psum, cmax, crs);
  // 7) softmax-apply + per-head 64x64 matmul -> out_attn (bf16, overwrites kv)
  attn_apply<<<dim3(NN / 128, HH, BB), 256, 0, stream>>>(qbuf, ctx, cmax, crs, oattn);
  // 8) x2 = out_attn @ Wo + bo + x   (fp32, overwrites q)
  gemm256<1><<<dim3((unsigned)(nm * (DD / 256))), 512, 0, stream>>>(
      oattn, WoT, bo, x, qbuf, DD, DD, DD, DD, DD / 256);
  float* x2 = qbuf;
  // 9) LN_f(x2) -> bf16
  ln_rows<<<dim3((unsigned)MR), 256, 0, stream>>>(x2, ln_f_g, ln_f_b, lnbuf);
  // 10) MLP: h = silu(x2ln @ W1 + b1); out = x2 + h @ W2 + b2
  for (int c0 = 0; c0 < 4096; c0 += CS) {
    gemm256<3><<<dim3((unsigned)(nm * (CS / 256))), 512, 0, stream>>>(
        lnbuf, W1T + (long)c0 * DD, b1 + c0, nullptr, hbuf, CS, DD, DD, DD, CS / 256);
    gemm256<1><<<dim3((unsigned)(nm * (DD / 256))), 512, 0, stream>>>(
        hbuf, W2T + c0, (c0 == 0) ? b2 : nullptr,
        (c0 == 0) ? (const float*)x2 : (const float*)outp, outp, DD, CS, CS, 4096, DD / 256);
  }
}

// Round 7
// 1292.647 us; speedup vs baseline: 1.3695x; 1.0118x over previous
//
#include <hip/hip_runtime.h>
#include <stdint.h>
#include <stddef.h>

#define BB 8
#define NN 4096
#define MTOK 1024
#define DD 1024
#define HH 16
#define EPSF 1e-6f
static const float SCALE_F = 0.125f; // HD^-0.5, HD=64

typedef __attribute__((ext_vector_type(4))) float f32x4;
typedef __attribute__((ext_vector_type(8))) short bf16x8;

__device__ __forceinline__ short f2bf(float f) {
  union { float f; uint32_t u; } x; x.f = f;
  uint32_t r = (x.u + 0x7fffu + ((x.u >> 16) & 1u)) >> 16;
  return (short)(uint16_t)r;
}
__device__ __forceinline__ float bf2f(short s) {
  union { uint32_t u; float f; } x; x.u = ((uint32_t)(uint16_t)s) << 16;
  return x.f;
}

#if defined(__HIP_DEVICE_COMPILE__) && __has_builtin(__builtin_amdgcn_global_load_lds)
#define USE_GLOAD_LDS 1
#else
#define USE_GLOAD_LDS 0
#endif

#define BAR() __builtin_amdgcn_s_barrier()
#define LGKM0()                                        \
  do {                                                 \
    asm volatile("s_waitcnt lgkmcnt(0)" ::: "memory"); \
    __builtin_amdgcn_sched_barrier(0);                 \
  } while (0)
#define LGKM8() asm volatile("s_waitcnt lgkmcnt(8)" ::: "memory")
#if USE_GLOAD_LDS
#define VMW6() asm volatile("s_waitcnt vmcnt(6)" ::: "memory")
#else
#define VMW6() asm volatile("s_waitcnt vmcnt(0) lgkmcnt(0)" ::: "memory")
#endif
#define VMW0() asm volatile("s_waitcnt vmcnt(0)" ::: "memory")

// ---------------------------------------------------------------------------
// 256x256 8-phase bf16 GEMM — exact m201 template schedule (T1..T5).
// C = A[M,K] @ BT[N,K]^T + bias. 512 thr = 8 waves (2M x 4N), BK=64,
// LDS 128 KiB: buf0{A@0,B@32K} buf1{A@64K,B@96K}. Swizzle byte^=((b>>7)&7)<<4
// applied on pre-swizzled global stage source (linear global_load_lds dest)
// and on ds_read base pointers (ks=1 = base^64).
// A LDS layout: [row>>7][MH=(row>>6)&1][row&63][128B]; stage half = MH.
// B LDS layout: [NH=(row>>5)&1][g2=row>>6][row&31][128B]; stage half = NH
//   (aligned with the NH read quadrants so stage regions == read regions).
// Phase p: [ds_read subtile][stage 1 half][lgkm8 if 12 rds][barrier]
//          [lgkmcnt(0)+sched_barrier][setprio1 16 MFMA setprio0][barrier].
// Reads/K-tile: P1=12 (A-MH0 + B-NH0), P2=4 (B-NH1), P3=8 (A-MH1), P4=0.
// vmcnt(6) ONLY at P4/P8 (counted, loads span phases — T4).
// Stage slots (iter base T0): P1 buf1.A1<-T0+1 | P2 b0.A0 P3 b0.B0 P4 b0.B1
// P5 b0.A1 <-T0+2 | P6 b1.A0 P7 b1.B0 P8 b1.B1 <-T0+3. Region-safe: each
// stage >=1 barrier after its region's last read; each read covered by the
// P4/P8 vmcnt(6) at least 3 phases earlier.
// EPI: 0 f32 acc+bias | 1 f32 acc+bias+resid | 2 bf16 acc+bias | 3 bf16 silu
// ---------------------------------------------------------------------------
__device__ __forceinline__ bf16x8 ldsld(const char* p, int off) {
  return *(const bf16x8*)(p + off);
}
template <int MH>
__device__ __forceinline__ void rdA8(const char* k0, const char* k1, bf16x8 a[4][2]) {
#pragma unroll
  for (int m = 0; m < 4; ++m) {
    a[m][0] = ldsld(k0, MH * 8192 + m * 2048);
    a[m][1] = ldsld(k1, MH * 8192 + m * 2048);
  }
}
template <int NH>
__device__ __forceinline__ void rdB4(const char* k0, const char* k1, bf16x8 b[2][2]) {
#pragma unroll
  for (int n = 0; n < 2; ++n) {
    b[n][0] = ldsld(k0, NH * 16384 + n * 2048);
    b[n][1] = ldsld(k1, NH * 16384 + n * 2048);
  }
}
// Stage A half MH (16KB): rows {MH*64..+64} u {128+MH*64..+64} of 256x64 tile.
__device__ __forceinline__ void stgA(char* smc, int base, const short* pg,
                                     int ld, int mh, int k, int w) {
#pragma unroll
  for (int i = 0; i < 2; ++i) {
    const short* src = pg + (long)(mh * 64 + i * 128) * ld + k;
    char* dst = smc + base + i * 16384 + mh * 8192 + w * 1024;
#if USE_GLOAD_LDS
    __builtin_amdgcn_global_load_lds(
        (const __attribute__((address_space(1))) void*)src,
        (__attribute__((address_space(3))) void*)dst, 16, 0, 0);
#else
    *(bf16x8*)(dst + (int)(threadIdx.x & 63) * 16) = *(const bf16x8*)src;
#endif
  }
}
// Stage B half NH (16KB): rows with (row>>5)&1 == h.
__device__ __forceinline__ void stgB(char* smc, int base, const short* pg,
                                     int ld, int h, int k, int w) {
#pragma unroll
  for (int i = 0; i < 2; ++i) {
    const short* src = pg + (long)(h * 32 + i * 128) * ld + k;
    char* dst = smc + base + h * 16384 + i * 8192 + w * 1024;
#if USE_GLOAD_LDS
    __builtin_amdgcn_global_load_lds(
        (const __attribute__((address_space(1))) void*)src,
        (__attribute__((address_space(3))) void*)dst, 16, 0, 0);
#else
    *(bf16x8*)(dst + (int)(threadIdx.x & 63) * 16) = *(const bf16x8*)src;
#endif
  }
}
template <int MH, int NH>
__device__ __forceinline__ void mq(const bf16x8 a[4][2], const bf16x8 b[2][2],
                                   f32x4 acc[8][4]) {
  __builtin_amdgcn_s_setprio(1);
#pragma unroll
  for (int m = 0; m < 4; ++m)
#pragma unroll
    for (int n = 0; n < 2; ++n) {
      f32x4 c = acc[MH * 4 + m][NH * 2 + n];
      c = __builtin_amdgcn_mfma_f32_16x16x32_bf16(a[m][0], b[n][0], c, 0, 0, 0);
      c = __builtin_amdgcn_mfma_f32_16x16x32_bf16(a[m][1], b[n][1], c, 0, 0, 0);
      acc[MH * 4 + m][NH * 2 + n] = c;
    }
  __builtin_amdgcn_s_setprio(0);
}

template <int EPI>
__global__ __launch_bounds__(512, 2) void gemm256(
    const short* __restrict__ A, const short* __restrict__ BT,
    const float* __restrict__ bias, const float* __restrict__ resid,
    void* __restrict__ outp, int N, int K, int lda, int ldb, int num_n) {
  __shared__ int4 smem4[131072 / 16];
  char* smc = (char*)smem4;
  const int t = threadIdx.x;
  const int w = t >> 6, lane = t & 63;
  const int wr = w >> 2, wc = w & 3;

  // bijective XCD swizzle (m204)
  const int nwg = gridDim.x, orig = blockIdx.x;
  const int q8 = nwg >> 3, r8 = nwg & 7;
  const int xcd = orig & 7, loc = orig >> 3;
  const int wg = (xcd < r8 ? xcd * (q8 + 1) : r8 * (q8 + 1) + (xcd - r8) * q8) + loc;
  // ROW-major tile mapping: consecutive wg (same XCD) share the A panel.
  const int bm = wg / num_n, bn = wg % num_n;

  const int T = K >> 6;  // K-tiles of 64 (even for all our K)

  // ds_read base pointers (swizzled; ks=1 = base^64; frag offsets carry-free)
  int LA = wr * 16384 + (lane & 15) * 128 + ((lane >> 4) << 4);
  LA ^= ((LA >> 7) & 7) << 4;
  int LB = wc * 4096 + (lane & 15) * 128 + ((lane >> 4) << 4);
  LB ^= ((LB >> 7) & 7) << 4;
  const char* pA0k0 = smc + LA;
  const char* pA0k1 = smc + (LA ^ 64);
  const char* pA1k0 = pA0k0 + 65536;
  const char* pA1k1 = pA0k1 + 65536;
  const char* pB0k0 = smc + 32768 + LB;
  const char* pB0k1 = smc + 32768 + (LB ^ 64);
  const char* pB1k0 = pB0k0 + 65536;
  const char* pB1k1 = pB0k1 + 65536;

  // stage source pointers (pre-swizzled per-thread row/col; same col swizzle)
  const int colswz = ((t & 7) ^ ((t >> 3) & 7)) * 8;
  const short* pAg = A + (long)(bm * 256 + (t >> 3)) * lda + colswz;
  const short* pBg =
      BT + (long)(bn * 256 + ((t >> 8) * 64 + ((t >> 3) & 31))) * ldb + colswz;

  f32x4 acc[8][4];
#pragma unroll
  for (int i = 0; i < 8; ++i)
#pragma unroll
    for (int j = 0; j < 4; ++j) acc[i][j] = (f32x4){0.f, 0.f, 0.f, 0.f};

  bf16x8 a[4][2], b0[2][2], b1[2][2];

  // ---- prologue: buf0 <- tile0 (4 halves), buf1 <- tile1 (A0,B0,B1)
  stgA(smc, 0, pAg, lda, 0, 0, w);
  stgB(smc, 32768, pBg, ldb, 0, 0, w);
  stgB(smc, 32768, pBg, ldb, 1, 0, w);
  stgA(smc, 0, pAg, lda, 1, 0, w);
  stgA(smc, 65536, pAg, lda, 0, 64, w);
  stgB(smc, 98304, pBg, ldb, 0, 64, w);
  stgB(smc, 98304, pBg, ldb, 1, 64, w);
  VMW6();  // buf0's 8 loads complete (<=6 outstanding = buf1's)
  BAR();

  for (int t2 = 0; t2 < T; t2 += 2) {
    const int k1 = (t2 + 1) * 64;
    const int k2 = (t2 + 2 < T ? t2 + 2 : 0) * 64;
    const int k3 = (t2 + 3 < T ? t2 + 3 : 0) * 64;
    // P1: rd A-MH0 + B-NH0 (12) | st buf1.A1<-t2+1 | MFMA(MH0,NH0)
    rdA8<0>(pA0k0, pA0k1, a);
    rdB4<0>(pB0k0, pB0k1, b0);
    stgA(smc, 65536, pAg, lda, 1, k1, w);
    LGKM8();
    BAR(); LGKM0();
    mq<0, 0>(a, b0, acc);
    BAR();
    // P2: rd B-NH1 (4) | st buf0.A0<-t2+2 | MFMA(MH0,NH1)
    rdB4<1>(pB0k0, pB0k1, b1);
    stgA(smc, 0, pAg, lda, 0, k2, w);
    BAR(); LGKM0();
    mq<0, 1>(a, b1, acc);
    BAR();
    // P3: rd A-MH1 (8) | st buf0.B0<-t2+2 | MFMA(MH1,NH0)
    rdA8<1>(pA0k0, pA0k1, a);
    stgB(smc, 32768, pBg, ldb, 0, k2, w);
    BAR(); LGKM0();
    mq<1, 0>(a, b0, acc);
    BAR();
    // P4: st buf0.B1<-t2+2 | vmcnt(6) | MFMA(MH1,NH1)
    stgB(smc, 32768, pBg, ldb, 1, k2, w);
    VMW6();
    BAR();
    mq<1, 1>(a, b1, acc);
    BAR();
    // P5: rd buf1 A-MH0 + B-NH0 (12) | st buf0.A1<-t2+2 | MFMA
    rdA8<0>(pA1k0, pA1k1, a);
    rdB4<0>(pB1k0, pB1k1, b0);
    stgA(smc, 0, pAg, lda, 1, k2, w);
    LGKM8();
    BAR(); LGKM0();
    mq<0, 0>(a, b0, acc);
    BAR();
    // P6: rd buf1 B-NH1 (4) | st buf1.A0<-t2+3 | MFMA
    rdB4<1>(pB1k0, pB1k1, b1);
    stgA(smc, 65536, pAg, lda, 0, k3, w);
    BAR(); LGKM0();
    mq<0, 1>(a, b1, acc);
    BAR();
    // P7: rd buf1 A-MH1 (8) | st buf1.B0<-t2+3 | MFMA
    rdA8<1>(pA1k0, pA1k1, a);
    stgB(smc, 98304, pBg, ldb, 0, k3, w);
    BAR(); LGKM0();
    mq<1, 0>(a, b0, acc);
    BAR();
    // P8: st buf1.B1<-t2+3 | vmcnt(6) | MFMA
    stgB(smc, 98304, pBg, ldb, 1, k3, w);
    VMW6();
    BAR();
    mq<1, 1>(a, b1, acc);
    BAR();
  }
  VMW0();

  // ---- epilogue ----
  const int r0 = bm * 256 + wr * 128 + ((lane >> 4) << 2);
  const int c0 = bn * 256 + wc * 64 + (lane & 15);
#pragma unroll
  for (int mi = 0; mi < 8; ++mi) {
#pragma unroll
    for (int ni = 0; ni < 4; ++ni) {
      const int col = c0 + ni * 16;
      const float bv = bias ? bias[col] : 0.f;
#pragma unroll
      for (int rr = 0; rr < 4; ++rr) {
        const int row = r0 + mi * 16 + rr;
        const long idx = (long)row * N + col;
        float v = acc[mi][ni][rr] + bv;
        if (EPI == 0) {
          ((float*)outp)[idx] = v;
        } else if (EPI == 1) {
          ((float*)outp)[idx] = v + resid[idx];
        } else if (EPI == 2) {
          ((short*)outp)[idx] = f2bf(v);
        } else {
          v = v / (1.f + __expf(-v));
          ((short*)outp)[idx] = f2bf(v);
        }
      }
    }
  }
}

// ---------------------------------------------------------------------------
// Row LayerNorm over D=1024, fp32 in -> bf16 out. One block (256 thr) per row.
// ---------------------------------------------------------------------------
__global__ __launch_bounds__(256) void ln_rows(const float* __restrict__ in,
                                               const float* __restrict__ g,
                                               const float* __restrict__ bta,
                                               short* __restrict__ outp) {
  const int row = blockIdx.x;
  const int t = threadIdx.x;
  const float4 v = ((const float4*)(in + (long)row * DD))[t];
  float s = v.x + v.y + v.z + v.w;
  float ss = v.x * v.x + v.y * v.y + v.z * v.z + v.w * v.w;
#pragma unroll
  for (int off = 1; off < 64; off <<= 1) {
    s += __shfl_xor(s, off);
    ss += __shfl_xor(ss, off);
  }
  __shared__ float red[8];
  const int w = t >> 6, lane = t & 63;
  if (lane == 0) { red[w] = s; red[4 + w] = ss; }
  __syncthreads();
  s = red[0] + red[1] + red[2] + red[3];
  ss = red[4] + red[5] + red[6] + red[7];
  const float mu = s * (1.f / DD);
  const float var = ss * (1.f / DD) - mu * mu;
  const float rs = rsqrtf(var + EPSF);
  const float4 gv = ((const float4*)g)[t];
  const float4 bv = ((const float4*)bta)[t];
  short4 o;
  o.x = f2bf((v.x - mu) * rs * gv.x + bv.x);
  o.y = f2bf((v.y - mu) * rs * gv.y + bv.y);
  o.z = f2bf((v.z - mu) * rs * gv.z + bv.z);
  o.w = f2bf((v.w - mu) * rs * gv.w + bv.w);
  ((short4*)(outp + (long)row * DD))[t] = o;
}

// ---------------------------------------------------------------------------
// Transpose + fp32->bf16 convert: W[K][N] -> WT[N][K]. 64x64 tiles.
// ---------------------------------------------------------------------------
__global__ __launch_bounds__(256) void tconv(const float* __restrict__ W,
                                             short* __restrict__ WT, int K, int N) {
  __shared__ float tile[64][65];
  const int k0 = blockIdx.x * 64, n0 = blockIdx.y * 64;
  const int t = threadIdx.x;
  const int tr = t >> 6, tc = t & 63;
#pragma unroll
  for (int i = 0; i < 64; i += 4)
    tile[i + tr][tc] = W[(long)(k0 + i + tr) * N + n0 + tc];
  __syncthreads();
#pragma unroll
  for (int i = 0; i < 64; i += 4)
    WT[(long)(n0 + i + tr) * K + k0 + tc] = f2bf(tile[tc][i + tr]);
}

// ---------------------------------------------------------------------------
// ctx[b,h,d,e] = sum_m softmax_d(k[b,m,h,:])[d] * v[b,m,h,e].
// ---------------------------------------------------------------------------
__global__ __launch_bounds__(256) void ctx_kernel(const short* __restrict__ kv,
                                                  float* __restrict__ ctx) {
  const int bh = blockIdx.x;
  const int b = bh >> 4, h = bh & 15;
  const int t = threadIdx.x, g = t >> 6, lane = t & 63;
  __shared__ float ksm[4][64];
  __shared__ float vsm[4][64];
  float acc[16];
#pragma unroll
  for (int j = 0; j < 16; ++j) acc[j] = 0.f;
  const int d = t & 63;
  const int e0 = (t >> 6) * 16;
  const short* base = kv + (long)b * MTOK * 2048 + h * 64;
  for (int m0 = 0; m0 < MTOK; m0 += 4) {
    const long moff = (long)(m0 + g) * 2048;
    float kval = bf2f(base[moff + lane]);
    float vval = bf2f(base[moff + 1024 + lane]);
    float mx = kval;
#pragma unroll
    for (int off = 1; off < 64; off <<= 1) mx = fmaxf(mx, __shfl_xor(mx, off));
    float e = __expf(kval - mx);
    float sm = e;
#pragma unroll
    for (int off = 1; off < 64; off <<= 1) sm += __shfl_xor(sm, off);
    ksm[g][lane] = e / sm;
    vsm[g][lane] = vval;
    __syncthreads();
#pragma unroll
    for (int mm = 0; mm < 4; ++mm) {
      const float kd = ksm[mm][d];
#pragma unroll
      for (int j = 0; j < 16; ++j) acc[j] = fmaf(kd, vsm[mm][e0 + j], acc[j]);
    }
    __syncthreads();
  }
  float* cp = ctx + ((long)bh * 64 + d) * 64 + e0;
#pragma unroll
  for (int j = 0; j < 16; ++j) cp[j] = acc[j];
}

// ---------------------------------------------------------------------------
// Column softmax stats for q (softmax over the N axis per (b, column)).
// ---------------------------------------------------------------------------
__global__ __launch_bounds__(256) void qstat_part(const float* __restrict__ q,
                                                  float* __restrict__ pmax,
                                                  float* __restrict__ psum) {
  const int c = blockIdx.x * 256 + threadIdx.x;
  const int b = blockIdx.z, ch = blockIdx.y;
  const float* qp = q + ((long)b * NN + ch * 128) * DD + c;
  float mx = -1e30f, sm = 0.f;
  for (int r = 0; r < 128; ++r) {
    const float xv = qp[(long)r * DD];
    const float nm = fmaxf(mx, xv);
    sm = sm * __expf(mx - nm) + __expf(xv - nm);
    mx = nm;
  }
  const long idx = ((long)b * DD + c) * 32 + ch;
  pmax[idx] = mx;
  psum[idx] = sm;
}

__global__ __launch_bounds__(256) void qstat_comb(const float* __restrict__ pmax,
                                                  const float* __restrict__ psum,
                                                  float* __restrict__ cmax,
                                                  float* __restrict__ crs) {
  const int i = blockIdx.x * 256 + threadIdx.x;  // b*1024 + c
  const float* pm = pmax + (long)i * 32;
  const float* ps = psum + (long)i * 32;
  float mx = -1e30f;
#pragma unroll
  for (int ch = 0; ch < 32; ++ch) mx = fmaxf(mx, pm[ch]);
  float sm = 0.f;
#pragma unroll
  for (int ch = 0; ch < 32; ++ch) sm += ps[ch] * __expf(pm[ch] - mx);
  cmax[i] = mx;
  crs[i] = SCALE_F / sm;
}

// ---------------------------------------------------------------------------
// Fused: q_soft = exp(q-cmax)*crs (includes SCALE), out = q_soft @ ctx[b,h].
// ---------------------------------------------------------------------------
__global__ __launch_bounds__(256) void attn_apply(const float* __restrict__ q,
                                                  const float* __restrict__ ctx,
                                                  const float* __restrict__ cmax,
                                                  const float* __restrict__ crs,
                                                  short* __restrict__ outa) {
  const int b = blockIdx.z, h = blockIdx.y, n0 = blockIdx.x * 128;
  const int t = threadIdx.x, g = t >> 6, lane = t & 63;
  __shared__ float ctx_l[4096];
  __shared__ float cm[64], cs[64];
  __shared__ float qsm[4][64];
  const float* cp = ctx + (long)(b * HH + h) * 4096;
  for (int i = t; i < 4096; i += 256) ctx_l[i] = cp[i];
  if (t < 64) {
    cm[t] = cmax[(long)b * DD + h * 64 + t];
    cs[t] = crs[(long)b * DD + h * 64 + t];
  }
  __syncthreads();
  for (int i = 0; i < 32; ++i) {
    const int n = n0 + i * 4 + g;
    const long off = ((long)b * NN + n) * DD + h * 64;
    const float qv = q[off + lane];
    const float qs = __expf(qv - cm[lane]) * cs[lane];
    qsm[g][lane] = qs;  // same-wave LDS, no barrier needed
    float o = 0.f;
#pragma unroll
    for (int dd = 0; dd < 64; ++dd) o = fmaf(qsm[g][dd], ctx_l[dd * 64 + lane], o);
    outa[off + lane] = f2bf(o);
  }
}

// ---------------------------------------------------------------------------
extern "C" void kernel_launch(void* const* d_in, const int* in_sizes, int n_in,
                              void* d_out, int out_size, void* d_ws, size_t ws_size,
                              hipStream_t stream) {
  (void)in_sizes; (void)n_in; (void)out_size;
  const float* x      = (const float*)d_in[0];
  const float* wav    = (const float*)d_in[1];
  const float* ln_q_g = (const float*)d_in[2];
  const float* ln_q_b = (const float*)d_in[3];
  const float* Wq     = (const float*)d_in[4];
  const float* bq     = (const float*)d_in[5];
  const float* ln_kv_g= (const float*)d_in[6];
  const float* ln_kv_b= (const float*)d_in[7];
  const float* Wkv    = (const float*)d_in[8];
  const float* bkv    = (const float*)d_in[9];
  const float* Wo     = (const float*)d_in[10];
  const float* bo     = (const float*)d_in[11];
  const float* ln_f_g = (const float*)d_in[12];
  const float* ln_f_b = (const float*)d_in[13];
  const float* W1     = (const float*)d_in[14];
  const float* b1     = (const float*)d_in[15];
  const float* W2     = (const float*)d_in[16];
  const float* b2     = (const float*)d_in[17];
  float* outp = (float*)d_out;
  char* ws = (char*)d_ws;

  const long MR = (long)BB * NN;    // 32768 rows
  const long MKV = (long)BB * MTOK; // 8192 rows

  size_t off = 0;
  auto bump = [&](size_t bytes) {
    size_t o = off;
    off += (bytes + 255) & ~(size_t)255;
    return o;
  };
  short* WqT  = (short*)(ws + bump((size_t)DD * DD * 2));
  short* WkvT = (short*)(ws + bump((size_t)2048 * DD * 2));
  short* WoT  = (short*)(ws + bump((size_t)DD * DD * 2));
  short* W1T  = (short*)(ws + bump((size_t)4096 * DD * 2));
  short* W2T  = (short*)(ws + bump((size_t)DD * 4096 * 2));
  float* qbuf = (float*)(ws + bump((size_t)MR * DD * 4));   // later: x2 (fp32)
  short* lnbuf= (short*)(ws + bump((size_t)MR * DD * 2));   // xq_ln, later x2_ln
  float* ctx  = (float*)(ws + bump((size_t)BB * HH * 64 * 64 * 4));
  float* pmax = (float*)(ws + bump((size_t)BB * DD * 32 * 4));
  float* psum = (float*)(ws + bump((size_t)BB * DD * 32 * 4));
  float* cmax = (float*)(ws + bump((size_t)BB * DD * 4));
  float* crs  = (float*)(ws + bump((size_t)BB * DD * 4));
  const size_t dyn0 = off;
  short* wvln  = (short*)(ws + dyn0);
  short* kvbuf = (short*)(ws + dyn0 + (size_t)MKV * DD * 2);
  short* oattn = (short*)(ws + dyn0);  // reuses wvln+kv region (dead by then)
  short* hbuf  = (short*)(ws + dyn0);  // MLP phase (oattn dead by then)

  size_t avail = ws_size > dyn0 ? ws_size - dyn0 : 0;
  int CS = 4096;
  while (CS > 256 && (size_t)MR * CS * 2 > avail) CS >>= 1;

  const int nm = (int)(MR / 256);    // 128
  const int nmkv = (int)(MKV / 256); // 32

  // 1) weight convert+transpose to bf16 [N][K]
  tconv<<<dim3(DD / 64, DD / 64), 256, 0, stream>>>(Wq, WqT, DD, DD);
  tconv<<<dim3(DD / 64, 2048 / 64), 256, 0, stream>>>(Wkv, WkvT, DD, 2048);
  tconv<<<dim3(DD / 64, DD / 64), 256, 0, stream>>>(Wo, WoT, DD, DD);
  tconv<<<dim3(DD / 64, 4096 / 64), 256, 0, stream>>>(W1, W1T, DD, 4096);
  tconv<<<dim3(4096 / 64, DD / 64), 256, 0, stream>>>(W2, W2T, 4096, DD);

  // 2) LayerNorms -> bf16
  ln_rows<<<dim3((unsigned)MR), 256, 0, stream>>>(x, ln_q_g, ln_q_b, lnbuf);
  ln_rows<<<dim3((unsigned)MKV), 256, 0, stream>>>(wav, ln_kv_g, ln_kv_b, wvln);

  // 3) q = LN(x) @ Wq + bq   (fp32 out, needed for column softmax)
  gemm256<0><<<dim3((unsigned)(nm * (DD / 256))), 512, 0, stream>>>(
      lnbuf, WqT, bq, nullptr, qbuf, DD, DD, DD, DD, DD / 256);
  // 4) kv = LN(wav) @ Wkv + bkv  (bf16 out)
  gemm256<2><<<dim3((unsigned)(nmkv * (2048 / 256))), 512, 0, stream>>>(
      wvln, WkvT, bkv, nullptr, kvbuf, 2048, DD, DD, DD, 2048 / 256);
  // 5) context per (b,h)
  ctx_kernel<<<dim3(BB * HH), 256, 0, stream>>>(kvbuf, ctx);
  // 6) q column-softmax stats
  qstat_part<<<dim3(DD / 256, 32, BB), 256, 0, stream>>>(qbuf, pmax, psum);
  qstat_comb<<<dim3(BB * DD / 256), 256, 0, stream>>>(pmax, psum, cmax, crs);
  // 7) softmax-apply + per-head 64x64 matmul -> out_attn (bf16, overwrites kv)
  attn_apply<<<dim3(NN / 128, HH, BB), 256, 0, stream>>>(qbuf, ctx, cmax, crs, oattn);
  // 8) x2 = out_attn @ Wo + bo + x   (fp32, overwrites q)
  gemm256<1><<<dim3((unsigned)(nm * (DD / 256))), 512, 0, stream>>>(
      oattn, WoT, bo, x, qbuf, DD, DD, DD, DD, DD / 256);
  float* x2 = qbuf;
  // 9) LN_f(x2) -> bf16
  ln_rows<<<dim3((unsigned)MR), 256, 0, stream>>>(x2, ln_f_g, ln_f_b, lnbuf);
  // 10) MLP: h = silu(x2ln @ W1 + b1); out = x2 + h @ W2 + b2
  for (int c0 = 0; c0 < 4096; c0 += CS) {
    gemm256<3><<<dim3((unsigned)(nm * (CS / 256))), 512, 0, stream>>>(
        lnbuf, W1T + (long)c0 * DD, b1 + c0, nullptr, hbuf, CS, DD, DD, DD, CS / 256);
    gemm256<1><<<dim3((unsigned)(nm * (DD / 256))), 512, 0, stream>>>(
        hbuf, W2T + c0, (c0 == 0) ? b2 : nullptr,
        (c0 == 0) ? (const float*)x2 : (const float*)outp, outp, DD, CS, CS, 4096, DD / 256);
  }
}